// Round 7
// baseline (339.960 us; speedup 1.0000x reference)
//
#include <hip/hip_runtime.h>
#include <stdint.h>

// DreamGraphReasoner on MI355X (gfx950)
// Residual stream bf16-only (xb). Exact f32 mean: mean(x3)=mean(x0)+sum_h mean(t_h),
// partials fused into nodes_kernel (x0) and attn_mix (t_h, per-wave LDS slices).
// Sparse attention: node n=(g,l) attends to {(g',l): g'!=g} U {(g,l+1) if l<63}
// Fusion: attended@Whop = attn@(V@Whop) => QKV GEMM emits Q|K|VW_h directly.
// attn_mix v2: 1 wave = 4 queries x 16 lanes (32-elem d-slices); 4-step reduce,
// causal K/VW rows shared across the wave's 4 query groups.

typedef __bf16 bf16;
typedef __bf16 bf16x8 __attribute__((ext_vector_type(8)));
typedef __bf16 bf16x4 __attribute__((ext_vector_type(4)));
typedef float  f32x4  __attribute__((ext_vector_type(4)));

__device__ __forceinline__ void gload_lds16(const void* g, void* l) {
  __builtin_amdgcn_global_load_lds(
      (__attribute__((address_space(1))) void*)(size_t)(g),
      (__attribute__((address_space(3))) void*)(l), 16, 0, 0);
}

// ---------------- weight prep (coalesced reads; scattered writes L2-combine) --
__global__ void prep_weights(const float* __restrict__ Wq, const float* __restrict__ Wk,
                             const float* __restrict__ bq, const float* __restrict__ bk,
                             const float* __restrict__ Wv, const float* __restrict__ Whop,
                             const float* __restrict__ W1, const float* __restrict__ W2,
                             bf16* __restrict__ WtQK, float* __restrict__ bcat,
                             bf16* __restrict__ WhopTb, bf16* __restrict__ Wvb,
                             float* __restrict__ W1t, float* __restrict__ W2t) {
  int t = blockIdx.x * 256 + threadIdx.x;
  if (t < 524288) {                        // WtQK[sel*512+c][k] = W[k][c]
    int sel = t >> 18, k = (t >> 9) & 511, c = t & 511;
    const float* W = sel ? Wk : Wq;
    WtQK[(size_t)(sel * 512 + c) * 512 + k] = (bf16)W[k * 512 + c];
  } else if (t < 1048576) {                // W1t[o][d] = W1[d][o]
    int u = t - 524288;
    int d = u >> 10, o = u & 1023;
    W1t[(size_t)o * 512 + d] = W1[d * 1024 + o];
  } else if (t < 1572864) {                // W2t[o][d] = W2[d][o]
    int u = t - 1048576;
    int d = u >> 9, o = u & 511;
    W2t[(size_t)o * 1024 + d] = W2[d * 512 + o];
  } else if (t < 1573888) {
    int u = t - 1572864;
    bcat[u] = (u < 512) ? bq[u] : bk[u - 512];
  } else if (t < 2360320) {                // WhopTb[h*512+c][d] = Whop[h][d][c]
    int u = t - 1573888;
    int h = u >> 18, rem = u & 262143;
    int d = rem >> 9, c = rem & 511;
    WhopTb[(size_t)h * 262144 + (size_t)c * 512 + d] = (bf16)Whop[h * 262144 + d * 512 + c];
  } else if (t < 2622464) {                // Wvb = bf16(Wv)
    int u = t - 2360320;
    Wvb[u] = (bf16)Wv[u];
  }
}

// ---------------- bvw[h][c] = sum_d bv[d] * Whop[h][d][c]  (wave per output) --
__global__ __launch_bounds__(256)
void bvw_kernel(const float* __restrict__ bv, const float* __restrict__ Whop,
                float* __restrict__ bvw) {
  int w = blockIdx.x * 4 + (threadIdx.x >> 6);  // 0..1535
  int lane = threadIdx.x & 63;
  int h = w >> 9, c = w & 511;
  int d0 = lane * 8;
  const float* wh = Whop + h * 262144 + c;
  float p = 0.f;
#pragma unroll
  for (int i = 0; i < 8; ++i) p += bv[d0 + i] * wh[(d0 + i) * 512];
#pragma unroll
  for (int off = 32; off; off >>= 1) p += __shfl_xor(p, off);
  if (lane == 0) bvw[w] = p;
}

// ---------------- node embeddings + fused x0 mean partials -------------------
__global__ __launch_bounds__(128)
void nodes_kernel(const float4* __restrict__ w, const float4* __restrict__ a,
                  const float4* __restrict__ r, bf16x4* __restrict__ xb,
                  float4* __restrict__ partial0) {
  const int c = blockIdx.x;   // 0..127
  const int b = blockIdx.y;   // 0..15
  const int dq = threadIdx.x; // 0..127 (d = dq*4)
  float4 s = (float4){0.f, 0.f, 0.f, 0.f};
#pragma unroll 2
  for (int n = c * 8; n < c * 8 + 8; ++n) {
    size_t idx = ((size_t)(n * 16 + b)) * 128 + dq;   // float4 index
    float4 vw = w[idx], va = a[idx], vr = r[idx];
    float4 v;
    v.x = (vw.x + va.x + vr.x) * (1.f / 3.f);
    v.y = (vw.y + va.y + vr.y) * (1.f / 3.f);
    v.z = (vw.z + va.z + vr.z) * (1.f / 3.f);
    v.w = (vw.w + va.w + vr.w) * (1.f / 3.f);
    bf16x4 bv4;
    bv4[0] = (bf16)v.x; bv4[1] = (bf16)v.y; bv4[2] = (bf16)v.z; bv4[3] = (bf16)v.w;
    xb[idx] = bv4;
    s.x += v.x; s.y += v.y; s.z += v.z; s.w += v.w;
  }
  partial0[((size_t)c * 16 + b) * 128 + dq] = s;
}

// ---------------- plain bf16 MFMA GEMM: out(1536x512) = A @ Bt^T -------------
__global__ __launch_bounds__(256)
void gemm_plain(const bf16* __restrict__ A, const bf16* __restrict__ Bt,
                bf16* __restrict__ out) {
  constexpr int BK = 32;
  __shared__ __align__(16) bf16 As[128 * BK];
  __shared__ __align__(16) bf16 Bs[128 * BK];
  const int tid = threadIdx.x;
  const int wave = tid >> 6, lane = tid & 63;
  const int wr = wave >> 1, wc = wave & 1;
  const int m0 = blockIdx.x * 128;
  const int n0 = blockIdx.y * 128;
  const int srow = lane >> 2;
  const int skg = ((lane & 3) ^ ((lane >> 3) & 3)) * 8;
  const int fr = lane & 15;
  const int kq = (((lane >> 4) ^ ((lane >> 1) & 3)) & 3) * 8;

  f32x4 acc[4][4];
#pragma unroll
  for (int i = 0; i < 4; ++i)
#pragma unroll
    for (int j = 0; j < 4; ++j) acc[i][j] = (f32x4){0.f, 0.f, 0.f, 0.f};

  for (int kt = 0; kt < 512; kt += BK) {
    __syncthreads();
#pragma unroll
    for (int i = 0; i < 2; ++i) {
      int ch = wave * 2 + i;
      int row = ch * 16 + srow;
      gload_lds16(A + (size_t)(m0 + row) * 512 + kt + skg, &As[ch * 16 * BK]);
      gload_lds16(Bt + (size_t)(n0 + row) * 512 + kt + skg, &Bs[ch * 16 * BK]);
    }
    __syncthreads();

    bf16x8 af[4], bg[4];
#pragma unroll
    for (int i = 0; i < 4; ++i)
      af[i] = *(const bf16x8*)&As[(wr * 64 + i * 16 + fr) * BK + kq];
#pragma unroll
    for (int j = 0; j < 4; ++j)
      bg[j] = *(const bf16x8*)&Bs[(wc * 64 + j * 16 + fr) * BK + kq];
#pragma unroll
    for (int i = 0; i < 4; ++i)
#pragma unroll
      for (int j = 0; j < 4; ++j)
        acc[i][j] = __builtin_amdgcn_mfma_f32_16x16x32_bf16(af[i], bg[j], acc[i][j], 0, 0, 0);
  }

#pragma unroll
  for (int i = 0; i < 4; ++i) {
    int grow0 = m0 + wr * 64 + i * 16 + (lane >> 4) * 4;
#pragma unroll
    for (int j = 0; j < 4; ++j) {
      int gcol = n0 + wc * 64 + j * 16 + fr;
#pragma unroll
      for (int q = 0; q < 4; ++q)
        out[(size_t)(grow0 + q) * 512 + gcol] = (bf16)acc[i][j][q];
    }
  }
}

// ---------------- bf16 MFMA GEMM: QKW = A(16384x512) @ [WqT|WkT|WvwT]^T + bias
__global__ __launch_bounds__(256)
void gemm_qkw(const bf16* __restrict__ A, const bf16* __restrict__ BtQK,
              const bf16* __restrict__ BtVW, const float* __restrict__ biasQK,
              const float* __restrict__ biasVW, bf16* __restrict__ out) {
  constexpr int BK = 32;
  __shared__ __align__(16) bf16 As[128 * BK];
  __shared__ __align__(16) bf16 Bs[128 * BK];
  const int tid = threadIdx.x;
  const int wave = tid >> 6, lane = tid & 63;
  const int wr = wave >> 1, wc = wave & 1;
  const int m0 = blockIdx.x * 128;
  const int n0 = blockIdx.y * 128;
  const bf16* Bt = (n0 < 1024) ? BtQK : (BtVW - (size_t)1024 * 512);
  const float* bias = (n0 < 1024) ? biasQK : (biasVW - 1024);

  const int srow = lane >> 2;
  const int skg = ((lane & 3) ^ ((lane >> 3) & 3)) * 8;
  const int fr = lane & 15;
  const int kq = (((lane >> 4) ^ ((lane >> 1) & 3)) & 3) * 8;

  f32x4 acc[4][4];
#pragma unroll
  for (int i = 0; i < 4; ++i)
#pragma unroll
    for (int j = 0; j < 4; ++j) acc[i][j] = (f32x4){0.f, 0.f, 0.f, 0.f};

  for (int kt = 0; kt < 512; kt += BK) {
    __syncthreads();
#pragma unroll
    for (int i = 0; i < 2; ++i) {
      int ch = wave * 2 + i;
      int row = ch * 16 + srow;
      gload_lds16(A + (size_t)(m0 + row) * 512 + kt + skg, &As[ch * 16 * BK]);
      gload_lds16(Bt + (size_t)(n0 + row) * 512 + kt + skg, &Bs[ch * 16 * BK]);
    }
    __syncthreads();

    bf16x8 af[4], bg[4];
#pragma unroll
    for (int i = 0; i < 4; ++i)
      af[i] = *(const bf16x8*)&As[(wr * 64 + i * 16 + fr) * BK + kq];
#pragma unroll
    for (int j = 0; j < 4; ++j)
      bg[j] = *(const bf16x8*)&Bs[(wc * 64 + j * 16 + fr) * BK + kq];
#pragma unroll
    for (int i = 0; i < 4; ++i)
#pragma unroll
      for (int j = 0; j < 4; ++j)
        acc[i][j] = __builtin_amdgcn_mfma_f32_16x16x32_bf16(af[i], bg[j], acc[i][j], 0, 0, 0);
  }

#pragma unroll
  for (int i = 0; i < 4; ++i) {
    int grow0 = m0 + wr * 64 + i * 16 + (lane >> 4) * 4;
#pragma unroll
    for (int j = 0; j < 4; ++j) {
      int gcol = n0 + wc * 64 + j * 16 + fr;
      float bvv = bias[gcol];
#pragma unroll
      for (int q = 0; q < 4; ++q)
        out[(size_t)(grow0 + q) * 1536 + gcol] = (bf16)(acc[i][j][q] + bvv);
    }
  }
}

// ---------------- sparse masked attention + hop epilogue + t-mean partials ---
// Block = 256 threads = 4 waves = one (l,b) pair (16 queries).
// Wave: 4 query groups x 16 lanes; lane lam owns d-slice [lam*32, lam*32+32).
// Causal K/VW rows shared across the wave's 4 groups (same l,b).
// Score reduce: 4-step 16-lane butterfly. t-partials: 2 cross-group shuffles +
// per-wave LDS slice (stride 36 f32), 1 barrier, no atomics.
__global__ __launch_bounds__(256)
void attn_mix(const bf16* __restrict__ QKW, bf16* __restrict__ xb,
              const float* __restrict__ bhop, float* __restrict__ tpart,
              int first) {
  __shared__ float slice[4 * 16 * 36];    // [wave][lam][36]
  const int tid = threadIdx.x;
  const int wave = tid >> 6, lane = tid & 63;
  const int q = lane >> 4, lam = lane & 15;
  const int bid = blockIdx.x;
  const int p = ((bid & 7) << 7) | (bid >> 3);   // pair 0..1023, l-chunked per XCD
  const int l = p >> 4, b = p & 15;
  const int g = wave * 4 + q;
  const int r = (((g << 6) | l) << 4) | b;
  const int d0 = lam * 32;

  // Q slice -> f32 (reused for 17 dots)
  const bf16x8* qp = (const bf16x8*)(QKW + (size_t)r * 1536 + d0);
  float qf[32];
#pragma unroll
  for (int i = 0; i < 4; ++i) {
    bf16x8 v = qp[i];
#pragma unroll
    for (int e = 0; e < 8; ++e) qf[i * 8 + e] = (float)v[e];
  }

  int rows[17];
#pragma unroll
  for (int j = 0; j < 16; ++j) rows[j] = (((j << 6) | l) << 4) | b;
  rows[16] = (l < 63) ? (r + 16) : r;

  // scores: 16-lane split dot + 4-step butterfly
  float s[17];
#pragma unroll
  for (int j = 0; j < 17; ++j) {
    const bf16x8* kp = (const bf16x8*)(QKW + (size_t)rows[j] * 1536 + 512 + d0);
    float pt = 0.f;
#pragma unroll
    for (int i = 0; i < 4; ++i) {
      bf16x8 kv = kp[i];
#pragma unroll
      for (int e = 0; e < 8; ++e) pt += qf[i * 8 + e] * (float)kv[e];
    }
    pt += __shfl_xor(pt, 1);
    pt += __shfl_xor(pt, 2);
    pt += __shfl_xor(pt, 4);
    pt += __shfl_xor(pt, 8);
    pt *= 0.044194173824159216f;  // 1/sqrt(512)
    bool valid = (j < 16) ? (j != g) : (l < 63);
    s[j] = valid ? pt : -1e30f;
  }

  float mx = -1e30f;
#pragma unroll
  for (int j = 0; j < 17; ++j) mx = fmaxf(mx, s[j]);
  float sum = 0.f;
#pragma unroll
  for (int j = 0; j < 17; ++j) { s[j] = __expf(s[j] - mx); sum += s[j]; }
  const float inv = 1.f / sum;

  // PV: weighted mix over the 17 VW rows, 32 elems per lane
  float acc[32];
#pragma unroll
  for (int e = 0; e < 32; ++e) acc[e] = 0.f;
#pragma unroll
  for (int j = 0; j < 17; ++j) {
    const bf16x8* vp = (const bf16x8*)(QKW + (size_t)rows[j] * 1536 + 1024 + d0);
    float w = s[j] * inv;
#pragma unroll
    for (int i = 0; i < 4; ++i) {
      bf16x8 vv = vp[i];
#pragma unroll
      for (int e = 0; e < 8; ++e) acc[i * 8 + e] += w * (float)vv[e];
    }
  }

  // epilogue: t = relu(mix + bh); xb += t (bf16 RMW)
  size_t idx = (size_t)r * 512 + d0;
  bf16x8* xp = (bf16x8*)(xb + idx);
  const float4* bhp = (const float4*)(bhop + d0);
  float t[32];
#pragma unroll
  for (int i = 0; i < 4; ++i) {
    bf16x8 xo = xp[i];
    float4 bhA = bhp[i * 2], bhB = bhp[i * 2 + 1];
    float bhv[8] = {bhA.x, bhA.y, bhA.z, bhA.w, bhB.x, bhB.y, bhB.z, bhB.w};
    bf16x8 ov;
#pragma unroll
    for (int e = 0; e < 8; ++e) {
      float tv = fmaxf(acc[i * 8 + e] + bhv[e], 0.f);
      t[i * 8 + e] = tv;
      ov[e] = (bf16)((float)xo[e] + tv);
    }
    xp[i] = ov;
  }

  // t-mean partial: sum over the wave's 4 query groups (2 shuffles/elem),
  // then q==0 lanes store to the per-wave LDS slice.
#pragma unroll
  for (int e = 0; e < 32; ++e) {
    t[e] += __shfl_xor(t[e], 16);
    t[e] += __shfl_xor(t[e], 32);
  }
  if (q == 0) {
    float* sp = &slice[wave * 576 + lam * 36];
#pragma unroll
    for (int c = 0; c < 8; ++c)
      *(float4*)(sp + c * 4) = (float4){t[c * 4], t[c * 4 + 1], t[c * 4 + 2], t[c * 4 + 3]};
  }
  __syncthreads();

  // block total over 4 waves (=16 queries) -> tpart[p]
#pragma unroll
  for (int half = 0; half < 2; ++half) {
    int d = half * 256 + tid;
    float sv = 0.f;
#pragma unroll
    for (int w2 = 0; w2 < 4; ++w2)
      sv += slice[w2 * 576 + (d >> 5) * 36 + (d & 31)];
    float* tp = tpart + (size_t)p * 512 + d;
    if (first) *tp = sv;
    else       *tp += sv;
  }
}

// ---------------- agg[b][d] = (sum partial0 + sum tpart)/1024 ----------------
__global__ __launch_bounds__(128)
void agg_final(const float* __restrict__ partial0, const float* __restrict__ tpart,
               float* __restrict__ agg) {
  const int b = blockIdx.x, dc = blockIdx.y;
  const int d = dc * 128 + threadIdx.x;
  float s = 0.f;
  for (int c = 0; c < 128; ++c) s += partial0[((size_t)c * 16 + b) * 512 + d];
  for (int l = 0; l < 64; ++l)    // pair p = l*16 + b
    s += tpart[(size_t)(l * 16 + b) * 512 + d];
  agg[b * 512 + d] = s * (1.0f / 1024.0f);
}

// ---------------- final MLP ---------------------------------------------------
__global__ __launch_bounds__(256)
void mlp1(const float* __restrict__ agg, const float* __restrict__ W1t,
          const float* __restrict__ b1, float* __restrict__ hdn) {
  const int lane = threadIdx.x & 63;
  const int o = blockIdx.x * 4 + (threadIdx.x >> 6);
  const int b = lane & 15, q = lane >> 4;
  const float4* wp = (const float4*)(W1t + (size_t)o * 512 + q * 128);
  const float4* ap = (const float4*)(agg + b * 512 + q * 128);
  float acc = 0.f;
#pragma unroll
  for (int i = 0; i < 32; ++i) {
    float4 w = wp[i], a = ap[i];
    acc += w.x * a.x + w.y * a.y + w.z * a.z + w.w * a.w;
  }
  acc += __shfl_xor(acc, 16);
  acc += __shfl_xor(acc, 32);
  if (lane < 16) hdn[b * 1024 + o] = fmaxf(acc + b1[o], 0.f);
}

__global__ __launch_bounds__(256)
void mlp2(const float* __restrict__ hdn, const float* __restrict__ W2t,
          const float* __restrict__ b2, float* __restrict__ out) {
  const int lane = threadIdx.x & 63;
  const int o = blockIdx.x * 4 + (threadIdx.x >> 6);
  const int b = lane & 15, q = lane >> 4;
  const float4* wp = (const float4*)(W2t + (size_t)o * 1024 + q * 256);
  const float4* hp = (const float4*)(hdn + b * 1024 + q * 256);
  float acc = 0.f;
#pragma unroll
  for (int i = 0; i < 64; ++i) {
    float4 w = wp[i], h = hp[i];
    acc += w.x * h.x + w.y * h.y + w.z * h.z + w.w * h.w;
  }
  acc += __shfl_xor(acc, 16);
  acc += __shfl_xor(acc, 32);
  if (lane < 16) out[b * 512 + o] = acc + b2[o];
}

// ---------------- launch -----------------------------------------------------
extern "C" void kernel_launch(void* const* d_in, const int* in_sizes, int n_in,
                              void* d_out, int out_size, void* d_ws, size_t ws_size,
                              hipStream_t stream) {
  const float* what   = (const float*)d_in[0];
  const float* action = (const float*)d_in[1];
  const float* result = (const float*)d_in[2];
  const float* Wq = (const float*)d_in[3];
  const float* bq = (const float*)d_in[4];
  const float* Wk = (const float*)d_in[5];
  const float* bk = (const float*)d_in[6];
  const float* Wv = (const float*)d_in[7];
  const float* bv = (const float*)d_in[8];
  const float* Whop = (const float*)d_in[9];
  const float* bhop = (const float*)d_in[10];
  const float* W1 = (const float*)d_in[11];
  const float* b1 = (const float*)d_in[12];
  const float* W2 = (const float*)d_in[13];
  const float* b2 = (const float*)d_in[14];
  float* out = (float*)d_out;

  char* ws = (char*)d_ws;
  bf16*  xb     = (bf16*)(ws + 0);               // 16,777,216 B
  bf16*  QKW    = (bf16*)(ws + 16777216);        // 50,331,648 B (ld=1536)
  // WhopTb/Wvb alias QKW region: consumed by gemm_plain before hop 0 writes QKW
  bf16*  WhopTb = (bf16*)(ws + 16777216);        //  1,572,864 B (alias)
  bf16*  Wvb    = (bf16*)(ws + 18350080);        //    524,288 B (alias)
  bf16*  WtQK   = (bf16*)(ws + 67108864);        //  1,048,576 B
  bf16*  WvwT   = (bf16*)(ws + 68157440);        //  1,572,864 B (3 hops)
  float* bcat   = (float*)(ws + 69730304);       //      4,096 B
  float* bvw    = (float*)(ws + 69734400);       //      6,144 B
  float* W1t    = (float*)(ws + 69740544);       //  2,097,152 B
  float* W2t    = (float*)(ws + 71837696);       //  2,097,152 B
  float* part0  = (float*)(ws + 73934848);       //  4,194,304 B (128*16*512 f32)
  float* tpart  = (float*)(ws + 78129152);       //  2,097,152 B (1024*512 f32)
  float* agg    = (float*)(ws + 82323456);       //     32,768 B
  float* hdn    = (float*)(ws + 82356224);       //     65,536 B

  prep_weights<<<10244, 256, 0, stream>>>(Wq, Wk, bq, bk, Wv, Whop, W1, W2,
                                          WtQK, bcat, WhopTb, Wvb, W1t, W2t);
  bvw_kernel<<<384, 256, 0, stream>>>(bv, Whop, bvw);
  gemm_plain<<<dim3(12, 4), 256, 0, stream>>>(WhopTb, Wvb, WvwT);
  nodes_kernel<<<dim3(128, 16), 128, 0, stream>>>((const float4*)what, (const float4*)action,
                                                  (const float4*)result, (bf16x4*)xb,
                                                  (float4*)part0);
  for (int h = 0; h < 3; ++h) {
    gemm_qkw<<<dim3(128, 12), 256, 0, stream>>>(xb, WtQK, WvwT + h * 262144,
                                                bcat, bvw + h * 512, QKW);
    attn_mix<<<1024, 256, 0, stream>>>(QKW, xb, bhop + h * 512, tpart, h == 0 ? 1 : 0);
  }
  agg_final<<<dim3(16, 4), 128, 0, stream>>>(part0, tpart, agg);
  mlp1<<<256, 256, 0, stream>>>(agg, W1t, b1, hdn);
  mlp2<<<128, 256, 0, stream>>>(hdn, W2t, b2, out);
}

// Round 8
// 302.568 us; speedup vs baseline: 1.1236x; 1.1236x over previous
//
#include <hip/hip_runtime.h>
#include <stdint.h>

// DreamGraphReasoner on MI355X (gfx950)
// Residual stream bf16-only (xb). Exact f32 mean: mean(x3)=mean(x0)+sum_h mean(t_h),
// partials fused into nodes_kernel (x0) and attn_mix (t_h, per-wave LDS slices).
// Sparse attention: node n=(g,l) attends to {(g',l): g'!=g} U {(g,l+1) if l<63}
// Fusion: attended@Whop = attn@(V@Whop) => QKV GEMM emits Q|K|VW_h directly.
// attn_mix: R6 geometry (1 query/wave, 8 waves/block) — max TLP for gather+VALU.
// prep: output-coalesced gather transposes (writes exact, reads L2-absorbed).

typedef __bf16 bf16;
typedef __bf16 bf16x8 __attribute__((ext_vector_type(8)));
typedef __bf16 bf16x4 __attribute__((ext_vector_type(4)));
typedef float  f32x4  __attribute__((ext_vector_type(4)));

__device__ __forceinline__ void gload_lds16(const void* g, void* l) {
  __builtin_amdgcn_global_load_lds(
      (__attribute__((address_space(1))) void*)(size_t)(g),
      (__attribute__((address_space(3))) void*)(l), 16, 0, 0);
}

// ---------------- weight prep: OUTPUT-coalesced gather transposes -------------
// consecutive t -> consecutive output elements; scattered reads hit L2/L3.
__global__ void prep_weights(const float* __restrict__ Wq, const float* __restrict__ Wk,
                             const float* __restrict__ bq, const float* __restrict__ bk,
                             const float* __restrict__ Wv, const float* __restrict__ Whop,
                             const float* __restrict__ W1, const float* __restrict__ W2,
                             bf16* __restrict__ WtQK, float* __restrict__ bcat,
                             bf16* __restrict__ WhopTb, bf16* __restrict__ Wvb,
                             float* __restrict__ W1t, float* __restrict__ W2t) {
  int t = blockIdx.x * 256 + threadIdx.x;
  if (t < 524288) {                        // WtQK[(sel*512+c)*512+k] = W[k][c]
    int sel = t >> 18, c = (t >> 9) & 511, k = t & 511;
    const float* W = sel ? Wk : Wq;
    WtQK[t] = (bf16)W[k * 512 + c];
  } else if (t < 1048576) {                // W1t[o*512+d] = W1[d][o]
    int u = t - 524288;
    int o = u >> 9, d = u & 511;
    W1t[u] = W1[d * 1024 + o];
  } else if (t < 1572864) {                // W2t[o*1024+d] = W2[d][o]
    int u = t - 1048576;
    int o = u >> 10, d = u & 1023;
    W2t[u] = W2[d * 512 + o];
  } else if (t < 1573888) {
    int u = t - 1572864;
    bcat[u] = (u < 512) ? bq[u] : bk[u - 512];
  } else if (t < 2360320) {                // WhopTb[(h*512+c)*512+d] = Whop[h][d][c]
    int u = t - 1573888;
    int h = u >> 18, c = (u >> 9) & 511, d = u & 511;
    WhopTb[u] = (bf16)Whop[h * 262144 + d * 512 + c];
  } else if (t < 2622464) {                // Wvb = bf16(Wv)
    int u = t - 2360320;
    Wvb[u] = (bf16)Wv[u];
  }
}

// ---------------- bvw[h][c] = sum_d bv[d] * Whop[h][d][c]  (wave per output) --
__global__ __launch_bounds__(256)
void bvw_kernel(const float* __restrict__ bv, const float* __restrict__ Whop,
                float* __restrict__ bvw) {
  int w = blockIdx.x * 4 + (threadIdx.x >> 6);  // 0..1535
  int lane = threadIdx.x & 63;
  int h = w >> 9, c = w & 511;
  int d0 = lane * 8;
  const float* wh = Whop + h * 262144 + c;
  float p = 0.f;
#pragma unroll
  for (int i = 0; i < 8; ++i) p += bv[d0 + i] * wh[(d0 + i) * 512];
#pragma unroll
  for (int off = 32; off; off >>= 1) p += __shfl_xor(p, off);
  if (lane == 0) bvw[w] = p;
}

// ---------------- node embeddings + fused x0 mean partials -------------------
__global__ __launch_bounds__(128)
void nodes_kernel(const float4* __restrict__ w, const float4* __restrict__ a,
                  const float4* __restrict__ r, bf16x4* __restrict__ xb,
                  float4* __restrict__ partial0) {
  const int c = blockIdx.x;   // 0..127
  const int b = blockIdx.y;   // 0..15
  const int dq = threadIdx.x; // 0..127 (d = dq*4)
  float4 s = (float4){0.f, 0.f, 0.f, 0.f};
#pragma unroll 2
  for (int n = c * 8; n < c * 8 + 8; ++n) {
    size_t idx = ((size_t)(n * 16 + b)) * 128 + dq;   // float4 index
    float4 vw = w[idx], va = a[idx], vr = r[idx];
    float4 v;
    v.x = (vw.x + va.x + vr.x) * (1.f / 3.f);
    v.y = (vw.y + va.y + vr.y) * (1.f / 3.f);
    v.z = (vw.z + va.z + vr.z) * (1.f / 3.f);
    v.w = (vw.w + va.w + vr.w) * (1.f / 3.f);
    bf16x4 bv4;
    bv4[0] = (bf16)v.x; bv4[1] = (bf16)v.y; bv4[2] = (bf16)v.z; bv4[3] = (bf16)v.w;
    xb[idx] = bv4;
    s.x += v.x; s.y += v.y; s.z += v.z; s.w += v.w;
  }
  partial0[((size_t)c * 16 + b) * 128 + dq] = s;
}

// ---------------- plain bf16 MFMA GEMM: out(1536x512) = A @ Bt^T -------------
__global__ __launch_bounds__(256)
void gemm_plain(const bf16* __restrict__ A, const bf16* __restrict__ Bt,
                bf16* __restrict__ out) {
  constexpr int BK = 32;
  __shared__ __align__(16) bf16 As[128 * BK];
  __shared__ __align__(16) bf16 Bs[128 * BK];
  const int tid = threadIdx.x;
  const int wave = tid >> 6, lane = tid & 63;
  const int wr = wave >> 1, wc = wave & 1;
  const int m0 = blockIdx.x * 128;
  const int n0 = blockIdx.y * 128;
  const int srow = lane >> 2;
  const int skg = ((lane & 3) ^ ((lane >> 3) & 3)) * 8;
  const int fr = lane & 15;
  const int kq = (((lane >> 4) ^ ((lane >> 1) & 3)) & 3) * 8;

  f32x4 acc[4][4];
#pragma unroll
  for (int i = 0; i < 4; ++i)
#pragma unroll
    for (int j = 0; j < 4; ++j) acc[i][j] = (f32x4){0.f, 0.f, 0.f, 0.f};

  for (int kt = 0; kt < 512; kt += BK) {
    __syncthreads();
#pragma unroll
    for (int i = 0; i < 2; ++i) {
      int ch = wave * 2 + i;
      int row = ch * 16 + srow;
      gload_lds16(A + (size_t)(m0 + row) * 512 + kt + skg, &As[ch * 16 * BK]);
      gload_lds16(Bt + (size_t)(n0 + row) * 512 + kt + skg, &Bs[ch * 16 * BK]);
    }
    __syncthreads();

    bf16x8 af[4], bg[4];
#pragma unroll
    for (int i = 0; i < 4; ++i)
      af[i] = *(const bf16x8*)&As[(wr * 64 + i * 16 + fr) * BK + kq];
#pragma unroll
    for (int j = 0; j < 4; ++j)
      bg[j] = *(const bf16x8*)&Bs[(wc * 64 + j * 16 + fr) * BK + kq];
#pragma unroll
    for (int i = 0; i < 4; ++i)
#pragma unroll
      for (int j = 0; j < 4; ++j)
        acc[i][j] = __builtin_amdgcn_mfma_f32_16x16x32_bf16(af[i], bg[j], acc[i][j], 0, 0, 0);
  }

#pragma unroll
  for (int i = 0; i < 4; ++i) {
    int grow0 = m0 + wr * 64 + i * 16 + (lane >> 4) * 4;
#pragma unroll
    for (int j = 0; j < 4; ++j) {
      int gcol = n0 + wc * 64 + j * 16 + fr;
#pragma unroll
      for (int q = 0; q < 4; ++q)
        out[(size_t)(grow0 + q) * 512 + gcol] = (bf16)acc[i][j][q];
    }
  }
}

// ---------------- bf16 MFMA GEMM: QKW = A(16384x512) @ [WqT|WkT|WvwT]^T + bias
// 1D grid 1536 with bijective XCD swizzle; within an XCD, ntile varies fastest
// so each A-tile stays hot in that XCD's L2 across its 12 N-tiles.
__global__ __launch_bounds__(256)
void gemm_qkw(const bf16* __restrict__ A, const bf16* __restrict__ BtQK,
              const bf16* __restrict__ BtVW, const float* __restrict__ biasQK,
              const float* __restrict__ biasVW, bf16* __restrict__ out) {
  constexpr int BK = 32;
  __shared__ __align__(16) bf16 As[128 * BK];
  __shared__ __align__(16) bf16 Bs[128 * BK];
  const int tid = threadIdx.x;
  const int wave = tid >> 6, lane = tid & 63;
  const int wr = wave >> 1, wc = wave & 1;
  const int bid = blockIdx.x;                     // 0..1535, 1536 % 8 == 0
  const int swz = (bid & 7) * 192 + (bid >> 3);   // XCD-chunked
  const int m0 = (swz / 12) * 128;
  const int n0 = (swz % 12) * 128;
  const bf16* Bt = (n0 < 1024) ? BtQK : (BtVW - (size_t)1024 * 512);
  const float* bias = (n0 < 1024) ? biasQK : (biasVW - 1024);

  const int srow = lane >> 2;
  const int skg = ((lane & 3) ^ ((lane >> 3) & 3)) * 8;
  const int fr = lane & 15;
  const int kq = (((lane >> 4) ^ ((lane >> 1) & 3)) & 3) * 8;

  f32x4 acc[4][4];
#pragma unroll
  for (int i = 0; i < 4; ++i)
#pragma unroll
    for (int j = 0; j < 4; ++j) acc[i][j] = (f32x4){0.f, 0.f, 0.f, 0.f};

  for (int kt = 0; kt < 512; kt += BK) {
    __syncthreads();
#pragma unroll
    for (int i = 0; i < 2; ++i) {
      int ch = wave * 2 + i;
      int row = ch * 16 + srow;
      gload_lds16(A + (size_t)(m0 + row) * 512 + kt + skg, &As[ch * 16 * BK]);
      gload_lds16(Bt + (size_t)(n0 + row) * 512 + kt + skg, &Bs[ch * 16 * BK]);
    }
    __syncthreads();

    bf16x8 af[4], bg[4];
#pragma unroll
    for (int i = 0; i < 4; ++i)
      af[i] = *(const bf16x8*)&As[(wr * 64 + i * 16 + fr) * BK + kq];
#pragma unroll
    for (int j = 0; j < 4; ++j)
      bg[j] = *(const bf16x8*)&Bs[(wc * 64 + j * 16 + fr) * BK + kq];
#pragma unroll
    for (int i = 0; i < 4; ++i)
#pragma unroll
      for (int j = 0; j < 4; ++j)
        acc[i][j] = __builtin_amdgcn_mfma_f32_16x16x32_bf16(af[i], bg[j], acc[i][j], 0, 0, 0);
  }

#pragma unroll
  for (int i = 0; i < 4; ++i) {
    int grow0 = m0 + wr * 64 + i * 16 + (lane >> 4) * 4;
#pragma unroll
    for (int j = 0; j < 4; ++j) {
      int gcol = n0 + wc * 64 + j * 16 + fr;
      float bvv = bias[gcol];
#pragma unroll
      for (int q = 0; q < 4; ++q)
        out[(size_t)(grow0 + q) * 1536 + gcol] = (bf16)(acc[i][j][q] + bvv);
    }
  }
}

// ---------------- sparse masked attention + hop epilogue + t-mean partials ---
// R6 geometry: 512-thread blocks, 8 waves = 8 dreams per (l,b), 1 query/wave.
// t-mean partials via disjoint per-wave LDS slices (no atomics, 1 barrier).
__global__ __launch_bounds__(512)
void attn_mix(const bf16* __restrict__ QKW, bf16* __restrict__ xb,
              const float* __restrict__ bhop, float* __restrict__ tpart,
              int first) {
  __shared__ float slice[8 * 512];
  const int tid = threadIdx.x;
  const int bid = blockIdx.x;
  const int wid = ((bid & 7) << 8) | (bid >> 3);   // 256 blocks per XCD chunk
  const int lane = tid & 63;
  const int wv = tid >> 6;
  const int l = wid >> 5;
  const int b = (wid >> 1) & 15;
  const int g = ((wid & 1) << 3) | wv;
  const int r = (((g << 6) | l) << 4) | b;

  bf16x8 qv = *(const bf16x8*)(QKW + (size_t)r * 1536 + lane * 8);
  float qf[8];
#pragma unroll
  for (int i = 0; i < 8; ++i) qf[i] = (float)qv[i];

  int rows[17];
#pragma unroll
  for (int j = 0; j < 16; ++j) rows[j] = (((j << 6) | l) << 4) | b;
  rows[16] = (l < 63) ? (r + 16) : r;

  float s[17];
#pragma unroll
  for (int j = 0; j < 17; ++j) {
    const bf16* Krow = QKW + (size_t)rows[j] * 1536 + 512;
    bf16x8 kv = *(const bf16x8*)(Krow + lane * 8);
    float p = 0.f;
#pragma unroll
    for (int i = 0; i < 8; ++i) p += qf[i] * (float)kv[i];
#pragma unroll
    for (int off = 32; off; off >>= 1) p += __shfl_xor(p, off);
    p *= 0.044194173824159216f;  // 1/sqrt(512)
    bool valid = (j < 16) ? (j != g) : (l < 63);
    s[j] = valid ? p : -1e30f;
  }

  float mx = -1e30f;
#pragma unroll
  for (int j = 0; j < 17; ++j) mx = fmaxf(mx, s[j]);
  float pr[17], sum = 0.f;
#pragma unroll
  for (int j = 0; j < 17; ++j) { pr[j] = __expf(s[j] - mx); sum += pr[j]; }
  float inv = 1.f / sum;

  float acc[8] = {0, 0, 0, 0, 0, 0, 0, 0};
#pragma unroll
  for (int j = 0; j < 17; ++j) {
    const bf16* Vrow = QKW + (size_t)rows[j] * 1536 + 1024;
    bf16x8 vv = *(const bf16x8*)(Vrow + lane * 8);
    float w = pr[j] * inv;
#pragma unroll
    for (int i = 0; i < 8; ++i) acc[i] += w * (float)vv[i];
  }

  // epilogue: t = relu(mix+bh); xb += t (bf16 RMW, row owned by this wave)
  const int d0 = lane * 8;
  size_t idx = (size_t)r * 512 + d0;
  bf16x8 xo = *(const bf16x8*)(xb + idx);
  float4 bh0 = *(const float4*)(bhop + d0);
  float4 bh1 = *(const float4*)(bhop + d0 + 4);
  float bh[8] = {bh0.x, bh0.y, bh0.z, bh0.w, bh1.x, bh1.y, bh1.z, bh1.w};
  bf16x8 ov;
  float t[8];
#pragma unroll
  for (int i = 0; i < 8; ++i) {
    t[i] = fmaxf(acc[i] + bh[i], 0.f);
    ov[i] = (bf16)((float)xo[i] + t[i]);
  }
  *(bf16x8*)(xb + idx) = ov;

  // per-wave slice stores (disjoint, conflict-free), then cross-wave sum
  *(float4*)&slice[wv * 512 + lane * 4]       = (float4){t[0], t[1], t[2], t[3]};
  *(float4*)&slice[wv * 512 + 256 + lane * 4] = (float4){t[4], t[5], t[6], t[7]};
  __syncthreads();
  const int ll = tid >> 3, ii = tid & 7;
  const int p = (ii < 4) ? (ll * 4 + ii) : (256 + ll * 4 + (ii - 4));
  float s2 = 0.f;
#pragma unroll
  for (int w2 = 0; w2 < 8; ++w2) s2 += slice[w2 * 512 + p];
  float* tp = tpart + (size_t)wid * 512 + tid;
  if (first) *tp = s2;
  else       *tp += s2;
}

// ---------------- agg[b][d] = (sum partial0 + sum tpart)/1024 ----------------
__global__ __launch_bounds__(128)
void agg_final(const float* __restrict__ partial0, const float* __restrict__ tpart,
               float* __restrict__ agg) {
  const int b = blockIdx.x, dc = blockIdx.y;
  const int d = dc * 128 + threadIdx.x;
  float s = 0.f;
  for (int c = 0; c < 128; ++c) s += partial0[((size_t)c * 16 + b) * 512 + d];
  for (int k = 0; k < 128; ++k) {     // wid = l*32 + b*2 + half
    int wid = (k >> 1) * 32 + b * 2 + (k & 1);
    s += tpart[(size_t)wid * 512 + d];
  }
  agg[b * 512 + d] = s * (1.0f / 1024.0f);
}

// ---------------- final MLP ---------------------------------------------------
__global__ __launch_bounds__(256)
void mlp1(const float* __restrict__ agg, const float* __restrict__ W1t,
          const float* __restrict__ b1, float* __restrict__ hdn) {
  const int lane = threadIdx.x & 63;
  const int o = blockIdx.x * 4 + (threadIdx.x >> 6);
  const int b = lane & 15, q = lane >> 4;
  const float4* wp = (const float4*)(W1t + (size_t)o * 512 + q * 128);
  const float4* ap = (const float4*)(agg + b * 512 + q * 128);
  float acc = 0.f;
#pragma unroll
  for (int i = 0; i < 32; ++i) {
    float4 w = wp[i], a = ap[i];
    acc += w.x * a.x + w.y * a.y + w.z * a.z + w.w * a.w;
  }
  acc += __shfl_xor(acc, 16);
  acc += __shfl_xor(acc, 32);
  if (lane < 16) hdn[b * 1024 + o] = fmaxf(acc + b1[o], 0.f);
}

__global__ __launch_bounds__(256)
void mlp2(const float* __restrict__ hdn, const float* __restrict__ W2t,
          const float* __restrict__ b2, float* __restrict__ out) {
  const int lane = threadIdx.x & 63;
  const int o = blockIdx.x * 4 + (threadIdx.x >> 6);
  const int b = lane & 15, q = lane >> 4;
  const float4* wp = (const float4*)(W2t + (size_t)o * 1024 + q * 256);
  const float4* hp = (const float4*)(hdn + b * 1024 + q * 256);
  float acc = 0.f;
#pragma unroll
  for (int i = 0; i < 64; ++i) {
    float4 w = wp[i], h = hp[i];
    acc += w.x * h.x + w.y * h.y + w.z * h.z + w.w * h.w;
  }
  acc += __shfl_xor(acc, 16);
  acc += __shfl_xor(acc, 32);
  if (lane < 16) out[b * 512 + o] = acc + b2[o];
}

// ---------------- launch -----------------------------------------------------
extern "C" void kernel_launch(void* const* d_in, const int* in_sizes, int n_in,
                              void* d_out, int out_size, void* d_ws, size_t ws_size,
                              hipStream_t stream) {
  const float* what   = (const float*)d_in[0];
  const float* action = (const float*)d_in[1];
  const float* result = (const float*)d_in[2];
  const float* Wq = (const float*)d_in[3];
  const float* bq = (const float*)d_in[4];
  const float* Wk = (const float*)d_in[5];
  const float* bk = (const float*)d_in[6];
  const float* Wv = (const float*)d_in[7];
  const float* bv = (const float*)d_in[8];
  const float* Whop = (const float*)d_in[9];
  const float* bhop = (const float*)d_in[10];
  const float* W1 = (const float*)d_in[11];
  const float* b1 = (const float*)d_in[12];
  const float* W2 = (const float*)d_in[13];
  const float* b2 = (const float*)d_in[14];
  float* out = (float*)d_out;

  char* ws = (char*)d_ws;
  bf16*  xb     = (bf16*)(ws + 0);               // 16,777,216 B
  bf16*  QKW    = (bf16*)(ws + 16777216);        // 50,331,648 B (ld=1536)
  // WhopTb/Wvb alias QKW region: consumed by gemm_plain before hop 0 writes QKW
  bf16*  WhopTb = (bf16*)(ws + 16777216);        //  1,572,864 B (alias)
  bf16*  Wvb    = (bf16*)(ws + 18350080);        //    524,288 B (alias)
  bf16*  WtQK   = (bf16*)(ws + 67108864);        //  1,048,576 B
  bf16*  WvwT   = (bf16*)(ws + 68157440);        //  1,572,864 B (3 hops)
  float* bcat   = (float*)(ws + 69730304);       //      4,096 B
  float* bvw    = (float*)(ws + 69734400);       //      6,144 B
  float* W1t    = (float*)(ws + 69740544);       //  2,097,152 B
  float* W2t    = (float*)(ws + 71837696);       //  2,097,152 B
  float* part0  = (float*)(ws + 73934848);       //  4,194,304 B (128*16*512 f32)
  float* tpart  = (float*)(ws + 78129152);       //  4,194,304 B (2048*512 f32)
  float* agg    = (float*)(ws + 82323456);       //     32,768 B
  float* hdn    = (float*)(ws + 82356224);       //     65,536 B

  prep_weights<<<10244, 256, 0, stream>>>(Wq, Wk, bq, bk, Wv, Whop, W1, W2,
                                          WtQK, bcat, WhopTb, Wvb, W1t, W2t);
  bvw_kernel<<<384, 256, 0, stream>>>(bv, Whop, bvw);
  gemm_plain<<<dim3(12, 4), 256, 0, stream>>>(WhopTb, Wvb, WvwT);
  nodes_kernel<<<dim3(128, 16), 128, 0, stream>>>((const float4*)what, (const float4*)action,
                                                  (const float4*)result, (bf16x4*)xb,
                                                  (float4*)part0);
  for (int h = 0; h < 3; ++h) {
    gemm_qkw<<<1536, 256, 0, stream>>>(xb, WtQK, WvwT + h * 262144,
                                       bcat, bvw + h * 512, QKW);
    attn_mix<<<2048, 512, 0, stream>>>(QKW, xb, bhop + h * 512, tpart, h == 0 ? 1 : 0);
  }
  agg_final<<<dim3(16, 4), 128, 0, stream>>>(part0, tpart, agg);
  mlp1<<<256, 256, 0, stream>>>(agg, W1t, b1, hdn);
  mlp2<<<128, 256, 0, stream>>>(hdn, W2t, b2, out);
}

// Round 9
// 250.841 us; speedup vs baseline: 1.3553x; 1.2062x over previous
//
#include <hip/hip_runtime.h>
#include <stdint.h>

// DreamGraphReasoner on MI355X (gfx950)
// Residual stream bf16 ping-pong (xb0/xb1). Exact f32 mean via fused partials.
// Sparse attention: node n=(g,l) attends to {(g',l): g'!=g} U {(g,l+1) if l<63}
// Algebra: scores = Q.K = x M x^T with M = Wq Wk^T (bq=bk=0; row-const terms
// cancel in softmax). attended@Whop = attn@(V@Whop). Per-hop GEMM emits
// Y|VW_h (N=1024); attention keys read straight from the residual buffer.

typedef __bf16 bf16;
typedef __bf16 bf16x8 __attribute__((ext_vector_type(8)));
typedef __bf16 bf16x4 __attribute__((ext_vector_type(4)));
typedef float  f32x4  __attribute__((ext_vector_type(4)));

__device__ __forceinline__ void gload_lds16(const void* g, void* l) {
  __builtin_amdgcn_global_load_lds(
      (__attribute__((address_space(1))) void*)(size_t)(g),
      (__attribute__((address_space(3))) void*)(l), 16, 0, 0);
}

// ---------------- weight prep: output-coalesced casts/transposes --------------
__global__ void prep_weights(const float* __restrict__ Wq, const float* __restrict__ Wk,
                             const float* __restrict__ Wv, const float* __restrict__ Whop,
                             const float* __restrict__ W1, const float* __restrict__ W2,
                             bf16* __restrict__ Wqb, bf16* __restrict__ Wkb,
                             bf16* __restrict__ Wvb, bf16* __restrict__ WhopTb,
                             float* __restrict__ W1t, float* __restrict__ W2t,
                             float* __restrict__ zbias) {
  int t = blockIdx.x * 256 + threadIdx.x;
  if (t < 524288) {                        // W1t[o*512+d] = W1[d][o]
    int o = t >> 9, d = t & 511;
    W1t[t] = W1[d * 1024 + o];
  } else if (t < 1048576) {                // W2t[o*1024+d] = W2[d][o]
    int u = t - 524288;
    int o = u >> 10, d = u & 1023;
    W2t[u] = W2[d * 512 + o];
  } else if (t < 1835008) {                // WhopTb[(h*512+c)*512+d] = Whop[h][d][c]
    int u = t - 1048576;
    int h = u >> 18, c = (u >> 9) & 511, d = u & 511;
    WhopTb[u] = (bf16)Whop[h * 262144 + d * 512 + c];
  } else if (t < 2097152) {                // Wvb = bf16(Wv)
    int u = t - 1835008;
    Wvb[u] = (bf16)Wv[u];
  } else if (t < 2359296) {                // Wqb = bf16(Wq)
    int u = t - 2097152;
    Wqb[u] = (bf16)Wq[u];
  } else if (t < 2621440) {                // Wkb = bf16(Wk)
    int u = t - 2359296;
    Wkb[u] = (bf16)Wk[u];
  } else if (t < 2621952) {                // zero bias for Y section
    zbias[t - 2621440] = 0.f;
  }
}

// ---------------- bvw[h][c] = sum_d bv[d] * Whop[h][d][c]  (wave per output) --
__global__ __launch_bounds__(256)
void bvw_kernel(const float* __restrict__ bv, const float* __restrict__ Whop,
                float* __restrict__ bvw) {
  int w = blockIdx.x * 4 + (threadIdx.x >> 6);  // 0..1535
  int lane = threadIdx.x & 63;
  int h = w >> 9, c = w & 511;
  int d0 = lane * 8;
  const float* wh = Whop + h * 262144 + c;
  float p = 0.f;
#pragma unroll
  for (int i = 0; i < 8; ++i) p += bv[d0 + i] * wh[(d0 + i) * 512];
#pragma unroll
  for (int off = 32; off; off >>= 1) p += __shfl_xor(p, off);
  if (lane == 0) bvw[w] = p;
}

// ---------------- node embeddings + fused x0 mean partials -------------------
__global__ __launch_bounds__(128)
void nodes_kernel(const float4* __restrict__ w, const float4* __restrict__ a,
                  const float4* __restrict__ r, bf16x4* __restrict__ xb,
                  float4* __restrict__ partial0) {
  const int c = blockIdx.x;   // 0..127
  const int b = blockIdx.y;   // 0..15
  const int dq = threadIdx.x; // 0..127 (d = dq*4)
  float4 s = (float4){0.f, 0.f, 0.f, 0.f};
#pragma unroll 2
  for (int n = c * 8; n < c * 8 + 8; ++n) {
    size_t idx = ((size_t)(n * 16 + b)) * 128 + dq;   // float4 index
    float4 vw = w[idx], va = a[idx], vr = r[idx];
    float4 v;
    v.x = (vw.x + va.x + vr.x) * (1.f / 3.f);
    v.y = (vw.y + va.y + vr.y) * (1.f / 3.f);
    v.z = (vw.z + va.z + vr.z) * (1.f / 3.f);
    v.w = (vw.w + va.w + vr.w) * (1.f / 3.f);
    bf16x4 bv4;
    bv4[0] = (bf16)v.x; bv4[1] = (bf16)v.y; bv4[2] = (bf16)v.z; bv4[3] = (bf16)v.w;
    xb[idx] = bv4;
    s.x += v.x; s.y += v.y; s.z += v.z; s.w += v.w;
  }
  partial0[((size_t)c * 16 + b) * 128 + dq] = s;
}

// ---------------- plain bf16 MFMA GEMM: out(Mx512) = A @ Bt^T, ld 512 --------
__global__ __launch_bounds__(256)
void gemm_plain(const bf16* __restrict__ A, const bf16* __restrict__ Bt,
                bf16* __restrict__ out) {
  constexpr int BK = 32;
  __shared__ __align__(16) bf16 As[128 * BK];
  __shared__ __align__(16) bf16 Bs[128 * BK];
  const int tid = threadIdx.x;
  const int wave = tid >> 6, lane = tid & 63;
  const int wr = wave >> 1, wc = wave & 1;
  const int m0 = blockIdx.x * 128;
  const int n0 = blockIdx.y * 128;
  const int srow = lane >> 2;
  const int skg = ((lane & 3) ^ ((lane >> 3) & 3)) * 8;
  const int fr = lane & 15;
  const int kq = (((lane >> 4) ^ ((lane >> 1) & 3)) & 3) * 8;

  f32x4 acc[4][4];
#pragma unroll
  for (int i = 0; i < 4; ++i)
#pragma unroll
    for (int j = 0; j < 4; ++j) acc[i][j] = (f32x4){0.f, 0.f, 0.f, 0.f};

  for (int kt = 0; kt < 512; kt += BK) {
    __syncthreads();
#pragma unroll
    for (int i = 0; i < 2; ++i) {
      int ch = wave * 2 + i;
      int row = ch * 16 + srow;
      gload_lds16(A + (size_t)(m0 + row) * 512 + kt + skg, &As[ch * 16 * BK]);
      gload_lds16(Bt + (size_t)(n0 + row) * 512 + kt + skg, &Bs[ch * 16 * BK]);
    }
    __syncthreads();

    bf16x8 af[4], bg[4];
#pragma unroll
    for (int i = 0; i < 4; ++i)
      af[i] = *(const bf16x8*)&As[(wr * 64 + i * 16 + fr) * BK + kq];
#pragma unroll
    for (int j = 0; j < 4; ++j)
      bg[j] = *(const bf16x8*)&Bs[(wc * 64 + j * 16 + fr) * BK + kq];
#pragma unroll
    for (int i = 0; i < 4; ++i)
#pragma unroll
      for (int j = 0; j < 4; ++j)
        acc[i][j] = __builtin_amdgcn_mfma_f32_16x16x32_bf16(af[i], bg[j], acc[i][j], 0, 0, 0);
  }

#pragma unroll
  for (int i = 0; i < 4; ++i) {
    int grow0 = m0 + wr * 64 + i * 16 + (lane >> 4) * 4;
#pragma unroll
    for (int j = 0; j < 4; ++j) {
      int gcol = n0 + wc * 64 + j * 16 + fr;
#pragma unroll
      for (int q = 0; q < 4; ++q)
        out[(size_t)(grow0 + q) * 512 + gcol] = (bf16)acc[i][j][q];
    }
  }
}

// ---------------- bf16 MFMA GEMM: YW = A(16384x512) @ [BtY|WvwT_h]^T + bias --
// out ld 1024: cols 0-511 = Y = x M (zero bias), cols 512-1023 = VW_h (+bvw).
// 1D grid 1024, bijective XCD swizzle; ntile fastest within an XCD (A-reuse).
__global__ __launch_bounds__(256)
void gemm_qkw(const bf16* __restrict__ A, const bf16* __restrict__ BtY,
              const bf16* __restrict__ BtVW, const float* __restrict__ biasY,
              const float* __restrict__ biasVW, bf16* __restrict__ out) {
  constexpr int BK = 32;
  __shared__ __align__(16) bf16 As[128 * BK];
  __shared__ __align__(16) bf16 Bs[128 * BK];
  const int tid = threadIdx.x;
  const int wave = tid >> 6, lane = tid & 63;
  const int wr = wave >> 1, wc = wave & 1;
  const int bid = blockIdx.x;                     // 0..1023, 1024 % 8 == 0
  const int swz = (bid & 7) * 128 + (bid >> 3);   // XCD-chunked
  const int m0 = (swz >> 3) * 128;
  const int n0 = (swz & 7) * 128;
  const bf16* Bt = (n0 < 512) ? BtY : (BtVW - (size_t)512 * 512);
  const float* bias = (n0 < 512) ? biasY : (biasVW - 512);

  const int srow = lane >> 2;
  const int skg = ((lane & 3) ^ ((lane >> 3) & 3)) * 8;
  const int fr = lane & 15;
  const int kq = (((lane >> 4) ^ ((lane >> 1) & 3)) & 3) * 8;

  f32x4 acc[4][4];
#pragma unroll
  for (int i = 0; i < 4; ++i)
#pragma unroll
    for (int j = 0; j < 4; ++j) acc[i][j] = (f32x4){0.f, 0.f, 0.f, 0.f};

  for (int kt = 0; kt < 512; kt += BK) {
    __syncthreads();
#pragma unroll
    for (int i = 0; i < 2; ++i) {
      int ch = wave * 2 + i;
      int row = ch * 16 + srow;
      gload_lds16(A + (size_t)(m0 + row) * 512 + kt + skg, &As[ch * 16 * BK]);
      gload_lds16(Bt + (size_t)(n0 + row) * 512 + kt + skg, &Bs[ch * 16 * BK]);
    }
    __syncthreads();

    bf16x8 af[4], bg[4];
#pragma unroll
    for (int i = 0; i < 4; ++i)
      af[i] = *(const bf16x8*)&As[(wr * 64 + i * 16 + fr) * BK + kq];
#pragma unroll
    for (int j = 0; j < 4; ++j)
      bg[j] = *(const bf16x8*)&Bs[(wc * 64 + j * 16 + fr) * BK + kq];
#pragma unroll
    for (int i = 0; i < 4; ++i)
#pragma unroll
      for (int j = 0; j < 4; ++j)
        acc[i][j] = __builtin_amdgcn_mfma_f32_16x16x32_bf16(af[i], bg[j], acc[i][j], 0, 0, 0);
  }

#pragma unroll
  for (int i = 0; i < 4; ++i) {
    int grow0 = m0 + wr * 64 + i * 16 + (lane >> 4) * 4;
#pragma unroll
    for (int j = 0; j < 4; ++j) {
      int gcol = n0 + wc * 64 + j * 16 + fr;
      float bvv = bias[gcol];
#pragma unroll
      for (int q = 0; q < 4; ++q)
        out[(size_t)(grow0 + q) * 1024 + gcol] = (bf16)(acc[i][j][q] + bvv);
    }
  }
}

// ---------------- sparse masked attention + hop epilogue + t-mean partials ---
// 512-thread blocks, 8 waves = 8 dreams per (l,b), 1 query/wave (max TLP).
// scores = Y_i . x_j (keys from immutable xin); epilogue writes xout = xin + t.
__global__ __launch_bounds__(512)
void attn_mix(const bf16* __restrict__ YW, const bf16* __restrict__ xin,
              bf16* __restrict__ xout, const float* __restrict__ bhop,
              float* __restrict__ tpart, int first) {
  __shared__ float slice[8 * 512];
  const int tid = threadIdx.x;
  const int bid = blockIdx.x;
  const int wid = ((bid & 7) << 8) | (bid >> 3);   // 256 blocks per XCD chunk
  const int lane = tid & 63;
  const int wv = tid >> 6;
  const int l = wid >> 5;
  const int b = (wid >> 1) & 15;
  const int g = ((wid & 1) << 3) | wv;
  const int r = (((g << 6) | l) << 4) | b;

  bf16x8 qv = *(const bf16x8*)(YW + (size_t)r * 1024 + lane * 8);  // Y row
  float qf[8];
#pragma unroll
  for (int i = 0; i < 8; ++i) qf[i] = (float)qv[i];

  int rows[17];
#pragma unroll
  for (int j = 0; j < 16; ++j) rows[j] = (((j << 6) | l) << 4) | b;
  rows[16] = (l < 63) ? (r + 16) : r;

  float s[17];
#pragma unroll
  for (int j = 0; j < 17; ++j) {
    const bf16* Krow = xin + (size_t)rows[j] * 512;   // key = residual row
    bf16x8 kv = *(const bf16x8*)(Krow + lane * 8);
    float p = 0.f;
#pragma unroll
    for (int i = 0; i < 8; ++i) p += qf[i] * (float)kv[i];
#pragma unroll
    for (int off = 32; off; off >>= 1) p += __shfl_xor(p, off);
    p *= 0.044194173824159216f;  // 1/sqrt(512)
    bool valid = (j < 16) ? (j != g) : (l < 63);
    s[j] = valid ? p : -1e30f;
  }

  float mx = -1e30f;
#pragma unroll
  for (int j = 0; j < 17; ++j) mx = fmaxf(mx, s[j]);
  float pr[17], sum = 0.f;
#pragma unroll
  for (int j = 0; j < 17; ++j) { pr[j] = __expf(s[j] - mx); sum += pr[j]; }
  float inv = 1.f / sum;

  float acc[8] = {0, 0, 0, 0, 0, 0, 0, 0};
#pragma unroll
  for (int j = 0; j < 17; ++j) {
    const bf16* Vrow = YW + (size_t)rows[j] * 1024 + 512;   // VW section
    bf16x8 vv = *(const bf16x8*)(Vrow + lane * 8);
    float w = pr[j] * inv;
#pragma unroll
    for (int i = 0; i < 8; ++i) acc[i] += w * (float)vv[i];
  }

  // epilogue: t = relu(mix+bh); xout = xin + t (row exclusive to this wave)
  const int d0 = lane * 8;
  size_t idx = (size_t)r * 512 + d0;
  bf16x8 xo = *(const bf16x8*)(xin + idx);
  float4 bh0 = *(const float4*)(bhop + d0);
  float4 bh1 = *(const float4*)(bhop + d0 + 4);
  float bh[8] = {bh0.x, bh0.y, bh0.z, bh0.w, bh1.x, bh1.y, bh1.z, bh1.w};
  bf16x8 ov;
  float t[8];
#pragma unroll
  for (int i = 0; i < 8; ++i) {
    t[i] = fmaxf(acc[i] + bh[i], 0.f);
    ov[i] = (bf16)((float)xo[i] + t[i]);
  }
  *(bf16x8*)(xout + idx) = ov;

  // per-wave slice stores (disjoint, conflict-free), then cross-wave sum
  *(float4*)&slice[wv * 512 + lane * 4]       = (float4){t[0], t[1], t[2], t[3]};
  *(float4*)&slice[wv * 512 + 256 + lane * 4] = (float4){t[4], t[5], t[6], t[7]};
  __syncthreads();
  const int ll = tid >> 3, ii = tid & 7;
  const int p = (ii < 4) ? (ll * 4 + ii) : (256 + ll * 4 + (ii - 4));
  float s2 = 0.f;
#pragma unroll
  for (int w2 = 0; w2 < 8; ++w2) s2 += slice[w2 * 512 + p];
  float* tp = tpart + (size_t)wid * 512 + tid;
  if (first) *tp = s2;
  else       *tp += s2;
}

// ---------------- agg[b][d] = (sum partial0 + sum tpart)/1024 ----------------
__global__ __launch_bounds__(128)
void agg_final(const float* __restrict__ partial0, const float* __restrict__ tpart,
               float* __restrict__ agg) {
  const int b = blockIdx.x, dc = blockIdx.y;
  const int d = dc * 128 + threadIdx.x;
  float s = 0.f;
  for (int c = 0; c < 128; ++c) s += partial0[((size_t)c * 16 + b) * 512 + d];
  for (int k = 0; k < 128; ++k) {     // wid = l*32 + b*2 + half
    int wid = (k >> 1) * 32 + b * 2 + (k & 1);
    s += tpart[(size_t)wid * 512 + d];
  }
  agg[b * 512 + d] = s * (1.0f / 1024.0f);
}

// ---------------- final MLP ---------------------------------------------------
__global__ __launch_bounds__(256)
void mlp1(const float* __restrict__ agg, const float* __restrict__ W1t,
          const float* __restrict__ b1, float* __restrict__ hdn) {
  const int lane = threadIdx.x & 63;
  const int o = blockIdx.x * 4 + (threadIdx.x >> 6);
  const int b = lane & 15, q = lane >> 4;
  const float4* wp = (const float4*)(W1t + (size_t)o * 512 + q * 128);
  const float4* ap = (const float4*)(agg + b * 512 + q * 128);
  float acc = 0.f;
#pragma unroll
  for (int i = 0; i < 32; ++i) {
    float4 w = wp[i], a = ap[i];
    acc += w.x * a.x + w.y * a.y + w.z * a.z + w.w * a.w;
  }
  acc += __shfl_xor(acc, 16);
  acc += __shfl_xor(acc, 32);
  if (lane < 16) hdn[b * 1024 + o] = fmaxf(acc + b1[o], 0.f);
}

__global__ __launch_bounds__(256)
void mlp2(const float* __restrict__ hdn, const float* __restrict__ W2t,
          const float* __restrict__ b2, float* __restrict__ out) {
  const int lane = threadIdx.x & 63;
  const int o = blockIdx.x * 4 + (threadIdx.x >> 6);
  const int b = lane & 15, q = lane >> 4;
  const float4* wp = (const float4*)(W2t + (size_t)o * 1024 + q * 256);
  const float4* hp = (const float4*)(hdn + b * 1024 + q * 256);
  float acc = 0.f;
#pragma unroll
  for (int i = 0; i < 64; ++i) {
    float4 w = wp[i], h = hp[i];
    acc += w.x * h.x + w.y * h.y + w.z * h.z + w.w * h.w;
  }
  acc += __shfl_xor(acc, 16);
  acc += __shfl_xor(acc, 32);
  if (lane < 16) out[b * 512 + o] = acc + b2[o];
}

// ---------------- launch -----------------------------------------------------
extern "C" void kernel_launch(void* const* d_in, const int* in_sizes, int n_in,
                              void* d_out, int out_size, void* d_ws, size_t ws_size,
                              hipStream_t stream) {
  const float* what   = (const float*)d_in[0];
  const float* action = (const float*)d_in[1];
  const float* result = (const float*)d_in[2];
  const float* Wq = (const float*)d_in[3];
  const float* bq = (const float*)d_in[4];   (void)bq;  // zeros; cancels in softmax
  const float* Wk = (const float*)d_in[5];
  const float* bk = (const float*)d_in[6];   (void)bk;  // zeros; row-const in softmax
  const float* Wv = (const float*)d_in[7];
  const float* bv = (const float*)d_in[8];
  const float* Whop = (const float*)d_in[9];
  const float* bhop = (const float*)d_in[10];
  const float* W1 = (const float*)d_in[11];
  const float* b1 = (const float*)d_in[12];
  const float* W2 = (const float*)d_in[13];
  const float* b2 = (const float*)d_in[14];
  float* out = (float*)d_out;

  char* ws = (char*)d_ws;
  bf16*  xb0    = (bf16*)(ws + 0);               // 16,777,216 B
  bf16*  xb1    = (bf16*)(ws + 16777216);        // 16,777,216 B
  bf16*  QKW    = (bf16*)(ws + 33554432);        // 33,554,432 B (16384x1024)
  // aliases in QKW region: consumed by gemm_plain before hop 0 writes QKW
  bf16*  WhopTb = (bf16*)(ws + 33554432);        //  1,572,864 B (alias)
  bf16*  Wvb    = (bf16*)(ws + 35127296);        //    524,288 B (alias)
  bf16*  Wqb    = (bf16*)(ws + 35651584);        //    524,288 B (alias)
  bf16*  Wkb    = (bf16*)(ws + 36175872);        //    524,288 B (alias)
  bf16*  BtY    = (bf16*)(ws + 67108864);        //    524,288 B (M^T, persistent)
  bf16*  WvwT   = (bf16*)(ws + 67633152);        //  1,572,864 B (3 hops)
  float* zbias  = (float*)(ws + 69206016);       //      2,048 B
  float* bvw    = (float*)(ws + 69208064);       //      6,144 B
  float* W1t    = (float*)(ws + 69214208);       //  2,097,152 B
  float* W2t    = (float*)(ws + 71311360);       //  2,097,152 B
  float* part0  = (float*)(ws + 73408512);       //  4,194,304 B
  float* tpart  = (float*)(ws + 77602816);       //  4,194,304 B
  float* agg    = (float*)(ws + 81797120);       //     32,768 B
  float* hdn    = (float*)(ws + 81829888);       //     65,536 B

  prep_weights<<<10242, 256, 0, stream>>>(Wq, Wk, Wv, Whop, W1, W2,
                                          Wqb, Wkb, Wvb, WhopTb, W1t, W2t, zbias);
  bvw_kernel<<<384, 256, 0, stream>>>(bv, Whop, bvw);
  gemm_plain<<<dim3(12, 4), 256, 0, stream>>>(WhopTb, Wvb, WvwT);    // Wvw per hop
  gemm_plain<<<dim3(4, 4), 256, 0, stream>>>(Wkb, Wqb, BtY);         // M^T = Wk Wq^T
  nodes_kernel<<<dim3(128, 16), 128, 0, stream>>>((const float4*)what, (const float4*)action,
                                                  (const float4*)result, (bf16x4*)xb0,
                                                  (float4*)part0);
  bf16* xcur = xb0;
  bf16* xnxt = xb1;
  for (int h = 0; h < 3; ++h) {
    gemm_qkw<<<1024, 256, 0, stream>>>(xcur, BtY, WvwT + h * 262144,
                                       zbias, bvw + h * 512, QKW);
    attn_mix<<<2048, 512, 0, stream>>>(QKW, xcur, xnxt, bhop + h * 512, tpart,
                                       h == 0 ? 1 : 0);
    bf16* tmp = xcur; xcur = xnxt; xnxt = tmp;
  }
  agg_final<<<dim3(16, 4), 128, 0, stream>>>(part0, tpart, agg);
  mlp1<<<256, 256, 0, stream>>>(agg, W1t, b1, hdn);
  mlp2<<<128, 256, 0, stream>>>(hdn, W2t, b2, out);
}

// Round 10
// 249.309 us; speedup vs baseline: 1.3636x; 1.0061x over previous
//
#include <hip/hip_runtime.h>
#include <stdint.h>

// DreamGraphReasoner on MI355X (gfx950)
// Residual stream bf16 ping-pong (xb0/xb1). Exact f32 mean via fused partials.
// scores = x M x^T with M = Wq Wk^T (bq=bk=0 in this problem; row-consts cancel
// in softmax). attended@Whop = attn@(V@Whop). Per-hop GEMM emits Y|VW_h.
// attn_mix v3: block=16 waves=one (l,b) pair. Wave 0 computes the 16x16 score
// tile + temporal diag via MFMA (layouts identical to the working GEMM),
// softmax in D-layout, P->LDS; all 16 waves then PV (1 row/wave, max TLP).

typedef __bf16 bf16;
typedef __bf16 bf16x8 __attribute__((ext_vector_type(8)));
typedef __bf16 bf16x4 __attribute__((ext_vector_type(4)));
typedef float  f32x4  __attribute__((ext_vector_type(4)));

__device__ __forceinline__ void gload_lds16(const void* g, void* l) {
  __builtin_amdgcn_global_load_lds(
      (__attribute__((address_space(1))) void*)(size_t)(g),
      (__attribute__((address_space(3))) void*)(l), 16, 0, 0);
}

// ---------------- weight prep: output-coalesced casts/transposes --------------
__global__ void prep_weights(const float* __restrict__ Wq, const float* __restrict__ Wk,
                             const float* __restrict__ Wv, const float* __restrict__ Whop,
                             const float* __restrict__ W1, const float* __restrict__ W2,
                             bf16* __restrict__ Wqb, bf16* __restrict__ Wkb,
                             bf16* __restrict__ Wvb, bf16* __restrict__ WhopTb,
                             float* __restrict__ W1t, float* __restrict__ W2t,
                             float* __restrict__ zbias) {
  int t = blockIdx.x * 256 + threadIdx.x;
  if (t < 524288) {                        // W1t[o*512+d] = W1[d][o]
    int o = t >> 9, d = t & 511;
    W1t[t] = W1[d * 1024 + o];
  } else if (t < 1048576) {                // W2t[o*1024+d] = W2[d][o]
    int u = t - 524288;
    int o = u >> 10, d = u & 1023;
    W2t[u] = W2[d * 512 + o];
  } else if (t < 1835008) {                // WhopTb[(h*512+c)*512+d] = Whop[h][d][c]
    int u = t - 1048576;
    int h = u >> 18, c = (u >> 9) & 511, d = u & 511;
    WhopTb[u] = (bf16)Whop[h * 262144 + d * 512 + c];
  } else if (t < 2097152) {                // Wvb = bf16(Wv)
    int u = t - 1835008;
    Wvb[u] = (bf16)Wv[u];
  } else if (t < 2359296) {                // Wqb = bf16(Wq)
    int u = t - 2097152;
    Wqb[u] = (bf16)Wq[u];
  } else if (t < 2621440) {                // Wkb = bf16(Wk)
    int u = t - 2359296;
    Wkb[u] = (bf16)Wk[u];
  } else if (t < 2621952) {                // zero bias for Y section
    zbias[t - 2621440] = 0.f;
  }
}

// ---------------- bvw[h][c] = sum_d bv[d] * Whop[h][d][c]  (wave per output) --
__global__ __launch_bounds__(256)
void bvw_kernel(const float* __restrict__ bv, const float* __restrict__ Whop,
                float* __restrict__ bvw) {
  int w = blockIdx.x * 4 + (threadIdx.x >> 6);  // 0..1535
  int lane = threadIdx.x & 63;
  int h = w >> 9, c = w & 511;
  int d0 = lane * 8;
  const float* wh = Whop + h * 262144 + c;
  float p = 0.f;
#pragma unroll
  for (int i = 0; i < 8; ++i) p += bv[d0 + i] * wh[(d0 + i) * 512];
#pragma unroll
  for (int off = 32; off; off >>= 1) p += __shfl_xor(p, off);
  if (lane == 0) bvw[w] = p;
}

// ---------------- node embeddings + fused x0 mean partials -------------------
__global__ __launch_bounds__(128)
void nodes_kernel(const float4* __restrict__ w, const float4* __restrict__ a,
                  const float4* __restrict__ r, bf16x4* __restrict__ xb,
                  float4* __restrict__ partial0) {
  const int c = blockIdx.x;   // 0..127
  const int b = blockIdx.y;   // 0..15
  const int dq = threadIdx.x; // 0..127 (d = dq*4)
  float4 s = (float4){0.f, 0.f, 0.f, 0.f};
#pragma unroll 2
  for (int n = c * 8; n < c * 8 + 8; ++n) {
    size_t idx = ((size_t)(n * 16 + b)) * 128 + dq;   // float4 index
    float4 vw = w[idx], va = a[idx], vr = r[idx];
    float4 v;
    v.x = (vw.x + va.x + vr.x) * (1.f / 3.f);
    v.y = (vw.y + va.y + vr.y) * (1.f / 3.f);
    v.z = (vw.z + va.z + vr.z) * (1.f / 3.f);
    v.w = (vw.w + va.w + vr.w) * (1.f / 3.f);
    bf16x4 bv4;
    bv4[0] = (bf16)v.x; bv4[1] = (bf16)v.y; bv4[2] = (bf16)v.z; bv4[3] = (bf16)v.w;
    xb[idx] = bv4;
    s.x += v.x; s.y += v.y; s.z += v.z; s.w += v.w;
  }
  partial0[((size_t)c * 16 + b) * 128 + dq] = s;
}

// ---------------- plain bf16 MFMA GEMM: out(Mx512) = A @ Bt^T, ld 512 --------
__global__ __launch_bounds__(256)
void gemm_plain(const bf16* __restrict__ A, const bf16* __restrict__ Bt,
                bf16* __restrict__ out) {
  constexpr int BK = 32;
  __shared__ __align__(16) bf16 As[128 * BK];
  __shared__ __align__(16) bf16 Bs[128 * BK];
  const int tid = threadIdx.x;
  const int wave = tid >> 6, lane = tid & 63;
  const int wr = wave >> 1, wc = wave & 1;
  const int m0 = blockIdx.x * 128;
  const int n0 = blockIdx.y * 128;
  const int srow = lane >> 2;
  const int skg = ((lane & 3) ^ ((lane >> 3) & 3)) * 8;
  const int fr = lane & 15;
  const int kq = (((lane >> 4) ^ ((lane >> 1) & 3)) & 3) * 8;

  f32x4 acc[4][4];
#pragma unroll
  for (int i = 0; i < 4; ++i)
#pragma unroll
    for (int j = 0; j < 4; ++j) acc[i][j] = (f32x4){0.f, 0.f, 0.f, 0.f};

  for (int kt = 0; kt < 512; kt += BK) {
    __syncthreads();
#pragma unroll
    for (int i = 0; i < 2; ++i) {
      int ch = wave * 2 + i;
      int row = ch * 16 + srow;
      gload_lds16(A + (size_t)(m0 + row) * 512 + kt + skg, &As[ch * 16 * BK]);
      gload_lds16(Bt + (size_t)(n0 + row) * 512 + kt + skg, &Bs[ch * 16 * BK]);
    }
    __syncthreads();

    bf16x8 af[4], bg[4];
#pragma unroll
    for (int i = 0; i < 4; ++i)
      af[i] = *(const bf16x8*)&As[(wr * 64 + i * 16 + fr) * BK + kq];
#pragma unroll
    for (int j = 0; j < 4; ++j)
      bg[j] = *(const bf16x8*)&Bs[(wc * 64 + j * 16 + fr) * BK + kq];
#pragma unroll
    for (int i = 0; i < 4; ++i)
#pragma unroll
      for (int j = 0; j < 4; ++j)
        acc[i][j] = __builtin_amdgcn_mfma_f32_16x16x32_bf16(af[i], bg[j], acc[i][j], 0, 0, 0);
  }

#pragma unroll
  for (int i = 0; i < 4; ++i) {
    int grow0 = m0 + wr * 64 + i * 16 + (lane >> 4) * 4;
#pragma unroll
    for (int j = 0; j < 4; ++j) {
      int gcol = n0 + wc * 64 + j * 16 + fr;
#pragma unroll
      for (int q = 0; q < 4; ++q)
        out[(size_t)(grow0 + q) * 512 + gcol] = (bf16)acc[i][j][q];
    }
  }
}

// ---------------- bf16 MFMA GEMM: YW = A(16384x512) @ [BtY|WvwT_h]^T + bias --
__global__ __launch_bounds__(256)
void gemm_qkw(const bf16* __restrict__ A, const bf16* __restrict__ BtY,
              const bf16* __restrict__ BtVW, const float* __restrict__ biasY,
              const float* __restrict__ biasVW, bf16* __restrict__ out) {
  constexpr int BK = 32;
  __shared__ __align__(16) bf16 As[128 * BK];
  __shared__ __align__(16) bf16 Bs[128 * BK];
  const int tid = threadIdx.x;
  const int wave = tid >> 6, lane = tid & 63;
  const int wr = wave >> 1, wc = wave & 1;
  const int bid = blockIdx.x;                     // 0..1023
  const int swz = (bid & 7) * 128 + (bid >> 3);   // XCD-chunked
  const int m0 = (swz >> 3) * 128;
  const int n0 = (swz & 7) * 128;
  const bf16* Bt = (n0 < 512) ? BtY : (BtVW - (size_t)512 * 512);
  const float* bias = (n0 < 512) ? biasY : (biasVW - 512);

  const int srow = lane >> 2;
  const int skg = ((lane & 3) ^ ((lane >> 3) & 3)) * 8;
  const int fr = lane & 15;
  const int kq = (((lane >> 4) ^ ((lane >> 1) & 3)) & 3) * 8;

  f32x4 acc[4][4];
#pragma unroll
  for (int i = 0; i < 4; ++i)
#pragma unroll
    for (int j = 0; j < 4; ++j) acc[i][j] = (f32x4){0.f, 0.f, 0.f, 0.f};

  for (int kt = 0; kt < 512; kt += BK) {
    __syncthreads();
#pragma unroll
    for (int i = 0; i < 2; ++i) {
      int ch = wave * 2 + i;
      int row = ch * 16 + srow;
      gload_lds16(A + (size_t)(m0 + row) * 512 + kt + skg, &As[ch * 16 * BK]);
      gload_lds16(Bt + (size_t)(n0 + row) * 512 + kt + skg, &Bs[ch * 16 * BK]);
    }
    __syncthreads();

    bf16x8 af[4], bg[4];
#pragma unroll
    for (int i = 0; i < 4; ++i)
      af[i] = *(const bf16x8*)&As[(wr * 64 + i * 16 + fr) * BK + kq];
#pragma unroll
    for (int j = 0; j < 4; ++j)
      bg[j] = *(const bf16x8*)&Bs[(wc * 64 + j * 16 + fr) * BK + kq];
#pragma unroll
    for (int i = 0; i < 4; ++i)
#pragma unroll
      for (int j = 0; j < 4; ++j)
        acc[i][j] = __builtin_amdgcn_mfma_f32_16x16x32_bf16(af[i], bg[j], acc[i][j], 0, 0, 0);
  }

#pragma unroll
  for (int i = 0; i < 4; ++i) {
    int grow0 = m0 + wr * 64 + i * 16 + (lane >> 4) * 4;
#pragma unroll
    for (int j = 0; j < 4; ++j) {
      int gcol = n0 + wc * 64 + j * 16 + fr;
      float bvv = bias[gcol];
#pragma unroll
      for (int q = 0; q < 4; ++q)
        out[(size_t)(grow0 + q) * 1024 + gcol] = (bf16)(acc[i][j][q] + bvv);
    }
  }
}

// ---------------- sparse masked attention + hop epilogue + t-mean partials ---
// Block = 1024 threads = 16 waves = one (l,b) pair.
// Wave 0: MFMA scores S[g][g'] (A=Y rows, B=key rows; layouts as in gemm_qkw),
// + temporal diag via second MFMA chain; softmax in D-layout; P[16][17] -> LDS.
// All waves: PV for row g=wave (lane owns 8 d-elems), epilogue, t-partials.
__global__ __launch_bounds__(1024)
void attn_mix(const bf16* __restrict__ YW, const bf16* __restrict__ xin,
              bf16* __restrict__ xout, const float* __restrict__ bhop,
              float* __restrict__ tpart, int first) {
  __shared__ float P_lds[16 * 17];      // [query g][0..15 causal, 16 temporal]
  __shared__ float slice[16 * 512];
  const int tid = threadIdx.x;
  const int wv = tid >> 6;              // wave = query dream g
  const int lane = tid & 63;
  const int bid = blockIdx.x;
  const int pair = ((bid & 7) << 7) | (bid >> 3);  // 128 pairs per XCD chunk
  const int l = pair >> 4, b = pair & 15;
  const int lb = (l << 4) | b;          // row index for dream 0

  if (wv == 0) {
    // ---- scores via MFMA: D[row=query g][col=key g'] ----
    const int fr = lane & 15;           // A-row / B-col fragment index
    const int kg = (lane >> 4) * 8;     // k offset within 32-chunk
    const int rfr = (fr << 10) + lb;    // row for dream fr
    const int tro = (l < 63) ? 16 : 0;  // temporal key row offset (guarded)
    f32x4 Sc = (f32x4){0.f, 0.f, 0.f, 0.f};
    f32x4 Tc = (f32x4){0.f, 0.f, 0.f, 0.f};
#pragma unroll
    for (int s = 0; s < 16; ++s) {
      bf16x8 af = *(const bf16x8*)(YW + (size_t)rfr * 1024 + s * 32 + kg);
      bf16x8 bk = *(const bf16x8*)(xin + (size_t)rfr * 512 + s * 32 + kg);
      bf16x8 bt = *(const bf16x8*)(xin + (size_t)(rfr + tro) * 512 + s * 32 + kg);
      Sc = __builtin_amdgcn_mfma_f32_16x16x32_bf16(af, bk, Sc, 0, 0, 0);
      Tc = __builtin_amdgcn_mfma_f32_16x16x32_bf16(af, bt, Tc, 0, 0, 0);
    }
    // ---- softmax in D-layout: lane holds rows 4h+q of column c ----
    const int h = lane >> 4, c = lane & 15;
    const float scale = 0.044194173824159216f;   // 1/sqrt(512)
#pragma unroll
    for (int q = 0; q < 4; ++q) {
      int row = 4 * h + q;
      float sv = (c == row) ? -1e30f : Sc[q] * scale;             // self mask
      float ev = (c == row && l < 63) ? Tc[q] * scale : -1e30f;   // temporal on diag
      float mx = fmaxf(sv, ev);
      mx = fmaxf(mx, __shfl_xor(mx, 1));
      mx = fmaxf(mx, __shfl_xor(mx, 2));
      mx = fmaxf(mx, __shfl_xor(mx, 4));
      mx = fmaxf(mx, __shfl_xor(mx, 8));
      float pv = __expf(sv - mx);
      float pe = __expf(ev - mx);
      float dn = pv + pe;
      dn += __shfl_xor(dn, 1);
      dn += __shfl_xor(dn, 2);
      dn += __shfl_xor(dn, 4);
      dn += __shfl_xor(dn, 8);
      float invd = 1.f / dn;
      P_lds[row * 17 + c] = pv * invd;
      if (c == row) P_lds[row * 17 + 16] = pe * invd;
    }
  }
  __syncthreads();

  // ---- PV: row g = wv, lane owns d = lane*8..+7 ----
  const int g = wv;
  const int r = (g << 10) + lb;
  const int d0 = lane * 8;
  float acc[8] = {0.f, 0.f, 0.f, 0.f, 0.f, 0.f, 0.f, 0.f};
#pragma unroll
  for (int j = 0; j < 16; ++j) {
    float w = P_lds[g * 17 + j];      // wave-uniform LDS broadcast
    if (w > 0.f) {                    // skips j==g exactly (P=0)
      const bf16* Vrow = YW + ((size_t)((j << 10) + lb)) * 1024 + 512;
      bf16x8 vvv = *(const bf16x8*)(Vrow + d0);
#pragma unroll
      for (int i = 0; i < 8; ++i) acc[i] += w * (float)vvv[i];
    }
  }
  {
    float w = P_lds[g * 17 + 16];
    if (w > 0.f) {                    // zero at l==63
      const bf16* Vrow = YW + ((size_t)(r + 16)) * 1024 + 512;
      bf16x8 vvv = *(const bf16x8*)(Vrow + d0);
#pragma unroll
      for (int i = 0; i < 8; ++i) acc[i] += w * (float)vvv[i];
    }
  }

  // ---- epilogue: t = relu(mix+bh); xout = xin + t ----
  size_t idx = (size_t)r * 512 + d0;
  bf16x8 xo = *(const bf16x8*)(xin + idx);
  float4 bh0 = *(const float4*)(bhop + d0);
  float4 bh1 = *(const float4*)(bhop + d0 + 4);
  float bh[8] = {bh0.x, bh0.y, bh0.z, bh0.w, bh1.x, bh1.y, bh1.z, bh1.w};
  bf16x8 ov;
  float t[8];
#pragma unroll
  for (int i = 0; i < 8; ++i) {
    t[i] = fmaxf(acc[i] + bh[i], 0.f);
    ov[i] = (bf16)((float)xo[i] + t[i]);
  }
  *(bf16x8*)(xout + idx) = ov;

  // ---- t-mean partials: per-wave slice rows, then cross-wave sum ----
  *(float4*)&slice[wv * 512 + d0]     = (float4){t[0], t[1], t[2], t[3]};
  *(float4*)&slice[wv * 512 + d0 + 4] = (float4){t[4], t[5], t[6], t[7]};
  __syncthreads();
  if (tid < 512) {
    float sv = 0.f;
#pragma unroll
    for (int w2 = 0; w2 < 16; ++w2) sv += slice[w2 * 512 + tid];
    float* tp = tpart + (size_t)pair * 512 + tid;
    if (first) *tp = sv;
    else       *tp += sv;
  }
}

// ---------------- agg[b][d] = (sum partial0 + sum tpart)/1024 ----------------
__global__ __launch_bounds__(128)
void agg_final(const float* __restrict__ partial0, const float* __restrict__ tpart,
               float* __restrict__ agg) {
  const int b = blockIdx.x, dc = blockIdx.y;
  const int d = dc * 128 + threadIdx.x;
  float s = 0.f;
  for (int c = 0; c < 128; ++c) s += partial0[((size_t)c * 16 + b) * 512 + d];
  for (int l = 0; l < 64; ++l)          // pair = l*16 + b
    s += tpart[(size_t)(l * 16 + b) * 512 + d];
  agg[b * 512 + d] = s * (1.0f / 1024.0f);
}

// ---------------- final MLP ---------------------------------------------------
__global__ __launch_bounds__(256)
void mlp1(const float* __restrict__ agg, const float* __restrict__ W1t,
          const float* __restrict__ b1, float* __restrict__ hdn) {
  const int lane = threadIdx.x & 63;
  const int o = blockIdx.x * 4 + (threadIdx.x >> 6);
  const int b = lane & 15, q = lane >> 4;
  const float4* wp = (const float4*)(W1t + (size_t)o * 512 + q * 128);
  const float4* ap = (const float4*)(agg + b * 512 + q * 128);
  float acc = 0.f;
#pragma unroll
  for (int i = 0; i < 32; ++i) {
    float4 w = wp[i], a = ap[i];
    acc += w.x * a.x + w.y * a.y + w.z * a.z + w.w * a.w;
  }
  acc += __shfl_xor(acc, 16);
  acc += __shfl_xor(acc, 32);
  if (lane < 16) hdn[b * 1024 + o] = fmaxf(acc + b1[o], 0.f);
}

__global__ __launch_bounds__(256)
void mlp2(const float* __restrict__ hdn, const float* __restrict__ W2t,
          const float* __restrict__ b2, float* __restrict__ out) {
  const int lane = threadIdx.x & 63;
  const int o = blockIdx.x * 4 + (threadIdx.x >> 6);
  const int b = lane & 15, q = lane >> 4;
  const float4* wp = (const float4*)(W2t + (size_t)o * 1024 + q * 256);
  const float4* hp = (const float4*)(hdn + b * 1024 + q * 256);
  float acc = 0.f;
#pragma unroll
  for (int i = 0; i < 64; ++i) {
    float4 w = wp[i], h = hp[i];
    acc += w.x * h.x + w.y * h.y + w.z * h.z + w.w * h.w;
  }
  acc += __shfl_xor(acc, 16);
  acc += __shfl_xor(acc, 32);
  if (lane < 16) out[b * 512 + o] = acc + b2[o];
}

// ---------------- launch -----------------------------------------------------
extern "C" void kernel_launch(void* const* d_in, const int* in_sizes, int n_in,
                              void* d_out, int out_size, void* d_ws, size_t ws_size,
                              hipStream_t stream) {
  const float* what   = (const float*)d_in[0];
  const float* action = (const float*)d_in[1];
  const float* result = (const float*)d_in[2];
  const float* Wq = (const float*)d_in[3];
  const float* bq = (const float*)d_in[4];   (void)bq;  // zeros; cancels in softmax
  const float* Wk = (const float*)d_in[5];
  const float* bk = (const float*)d_in[6];   (void)bk;  // zeros; row-const in softmax
  const float* Wv = (const float*)d_in[7];
  const float* bv = (const float*)d_in[8];
  const float* Whop = (const float*)d_in[9];
  const float* bhop = (const float*)d_in[10];
  const float* W1 = (const float*)d_in[11];
  const float* b1 = (const float*)d_in[12];
  const float* W2 = (const float*)d_in[13];
  const float* b2 = (const float*)d_in[14];
  float* out = (float*)d_out;

  char* ws = (char*)d_ws;
  bf16*  xb0    = (bf16*)(ws + 0);               // 16,777,216 B
  bf16*  xb1    = (bf16*)(ws + 16777216);        // 16,777,216 B
  bf16*  QKW    = (bf16*)(ws + 33554432);        // 33,554,432 B (16384x1024)
  // aliases in QKW region: consumed by gemm_plain before hop 0 writes QKW
  bf16*  WhopTb = (bf16*)(ws + 33554432);        //  1,572,864 B (alias)
  bf16*  Wvb    = (bf16*)(ws + 35127296);        //    524,288 B (alias)
  bf16*  Wqb    = (bf16*)(ws + 35651584);        //    524,288 B (alias)
  bf16*  Wkb    = (bf16*)(ws + 36175872);        //    524,288 B (alias)
  bf16*  BtY    = (bf16*)(ws + 67108864);        //    524,288 B (M^T, persistent)
  bf16*  WvwT   = (bf16*)(ws + 67633152);        //  1,572,864 B (3 hops)
  float* zbias  = (float*)(ws + 69206016);       //      2,048 B
  float* bvw    = (float*)(ws + 69208064);       //      6,144 B
  float* W1t    = (float*)(ws + 69214208);       //  2,097,152 B
  float* W2t    = (float*)(ws + 71311360);       //  2,097,152 B
  float* part0  = (float*)(ws + 73408512);       //  4,194,304 B
  float* tpart  = (float*)(ws + 77602816);       //  2,097,152 B (1024*512 f32)
  float* agg    = (float*)(ws + 81797120);       //     32,768 B
  float* hdn    = (float*)(ws + 81829888);       //     65,536 B

  prep_weights<<<10242, 256, 0, stream>>>(Wq, Wk, Wv, Whop, W1, W2,
                                          Wqb, Wkb, Wvb, WhopTb, W1t, W2t, zbias);
  bvw_kernel<<<384, 256, 0, stream>>>(bv, Whop, bvw);
  gemm_plain<<<dim3(12, 4), 256, 0, stream>>>(WhopTb, Wvb, WvwT);    // Wvw per hop
  gemm_plain<<<dim3(4, 4), 256, 0, stream>>>(Wkb, Wqb, BtY);         // M^T = Wk Wq^T
  nodes_kernel<<<dim3(128, 16), 128, 0, stream>>>((const float4*)what, (const float4*)action,
                                                  (const float4*)result, (bf16x4*)xb0,
                                                  (float4*)part0);
  bf16* xcur = xb0;
  bf16* xnxt = xb1;
  for (int h = 0; h < 3; ++h) {
    gemm_qkw<<<1024, 256, 0, stream>>>(xcur, BtY, WvwT + h * 262144,
                                       zbias, bvw + h * 512, QKW);
    attn_mix<<<1024, 1024, 0, stream>>>(QKW, xcur, xnxt, bhop + h * 512, tpart,
                                        h == 0 ? 1 : 0);
    bf16* tmp = xcur; xcur = xnxt; xnxt = tmp;
  }
  agg_final<<<dim3(16, 4), 128, 0, stream>>>(part0, tpart, agg);
  mlp1<<<256, 256, 0, stream>>>(agg, W1t, b1, hdn);
  mlp2<<<128, 256, 0, stream>>>(hdn, W2t, b2, out);
}

// Round 11
// 240.069 us; speedup vs baseline: 1.4161x; 1.0385x over previous
//
#include <hip/hip_runtime.h>
#include <stdint.h>

// DreamGraphReasoner on MI355X (gfx950)
// Row layout: r = ((l*16+b) << 4) | g  — one (l,b) attention group = 16
// contiguous rows; temporal neighbor (l+1,b,g) = r + 256.
// Residual bf16 ping-pong (xb0/xb1). Exact f32 mean via fused partials.
// scores = x M x^T with M = Wq Wk^T (bq=bk=0; row-consts cancel in softmax).
// attended@Whop = attn@(V@Whop): per-hop GEMM emits Y|VW_h (ld 1024).
// attn_mix v4: block = 8 waves = one (l,b). VW tile staged to LDS
// (global_load_lds, contiguous); wave 0 MFMA scores from dense global rows;
// 8 waves PV 2 queries each from LDS.

typedef __bf16 bf16;
typedef __bf16 bf16x8 __attribute__((ext_vector_type(8)));
typedef __bf16 bf16x4 __attribute__((ext_vector_type(4)));
typedef float  f32x4  __attribute__((ext_vector_type(4)));

__device__ __forceinline__ void gload_lds16(const void* g, void* l) {
  __builtin_amdgcn_global_load_lds(
      (__attribute__((address_space(1))) void*)(size_t)(g),
      (__attribute__((address_space(3))) void*)(l), 16, 0, 0);
}

// ---------------- weight prep: output-coalesced casts/transposes --------------
__global__ void prep_weights(const float* __restrict__ Wq, const float* __restrict__ Wk,
                             const float* __restrict__ Wv, const float* __restrict__ Whop,
                             const float* __restrict__ W1, const float* __restrict__ W2,
                             bf16* __restrict__ Wqb, bf16* __restrict__ Wkb,
                             bf16* __restrict__ Wvb, bf16* __restrict__ WhopTb,
                             float* __restrict__ W1t, float* __restrict__ W2t,
                             float* __restrict__ zbias) {
  int t = blockIdx.x * 256 + threadIdx.x;
  if (t < 524288) {                        // W1t[o*512+d] = W1[d][o]
    int o = t >> 9, d = t & 511;
    W1t[t] = W1[d * 1024 + o];
  } else if (t < 1048576) {                // W2t[o*1024+d] = W2[d][o]
    int u = t - 524288;
    int o = u >> 10, d = u & 1023;
    W2t[u] = W2[d * 512 + o];
  } else if (t < 1835008) {                // WhopTb[(h*512+c)*512+d] = Whop[h][d][c]
    int u = t - 1048576;
    int h = u >> 18, c = (u >> 9) & 511, d = u & 511;
    WhopTb[u] = (bf16)Whop[h * 262144 + d * 512 + c];
  } else if (t < 2097152) {                // Wvb = bf16(Wv)
    int u = t - 1835008;
    Wvb[u] = (bf16)Wv[u];
  } else if (t < 2359296) {                // Wqb = bf16(Wq)
    int u = t - 2097152;
    Wqb[u] = (bf16)Wq[u];
  } else if (t < 2621440) {                // Wkb = bf16(Wk)
    int u = t - 2359296;
    Wkb[u] = (bf16)Wk[u];
  } else if (t < 2621952) {                // zero bias for Y section
    zbias[t - 2621440] = 0.f;
  }
}

// ---------------- bvw[h][c] = sum_d bv[d] * Whop[h][d][c]  (wave per output) --
__global__ __launch_bounds__(256)
void bvw_kernel(const float* __restrict__ bv, const float* __restrict__ Whop,
                float* __restrict__ bvw) {
  int w = blockIdx.x * 4 + (threadIdx.x >> 6);  // 0..1535
  int lane = threadIdx.x & 63;
  int h = w >> 9, c = w & 511;
  int d0 = lane * 8;
  const float* wh = Whop + h * 262144 + c;
  float p = 0.f;
#pragma unroll
  for (int i = 0; i < 8; ++i) p += bv[d0 + i] * wh[(d0 + i) * 512];
#pragma unroll
  for (int off = 32; off; off >>= 1) p += __shfl_xor(p, off);
  if (lane == 0) bvw[w] = p;
}

// ---------------- node embeddings + fused x0 mean partials -------------------
// node n = g*64+l (input order); output row r = ((l*16+b)<<4)|g
__global__ __launch_bounds__(128)
void nodes_kernel(const float4* __restrict__ w, const float4* __restrict__ a,
                  const float4* __restrict__ r, bf16x4* __restrict__ xb,
                  float4* __restrict__ partial0) {
  const int c = blockIdx.x;   // 0..127 (8 nodes each, g-major)
  const int b = blockIdx.y;   // 0..15
  const int dq = threadIdx.x; // 0..127 (d = dq*4)
  float4 s = (float4){0.f, 0.f, 0.f, 0.f};
#pragma unroll 2
  for (int n = c * 8; n < c * 8 + 8; ++n) {
    size_t iidx = ((size_t)(n * 16 + b)) * 128 + dq;   // input float4 index
    int g = n >> 6, l = n & 63;
    size_t oidx = ((size_t)(((l * 16 + b) << 4) | g)) * 128 + dq;
    float4 vw = w[iidx], va = a[iidx], vr = r[iidx];
    float4 v;
    v.x = (vw.x + va.x + vr.x) * (1.f / 3.f);
    v.y = (vw.y + va.y + vr.y) * (1.f / 3.f);
    v.z = (vw.z + va.z + vr.z) * (1.f / 3.f);
    v.w = (vw.w + va.w + vr.w) * (1.f / 3.f);
    bf16x4 bv4;
    bv4[0] = (bf16)v.x; bv4[1] = (bf16)v.y; bv4[2] = (bf16)v.z; bv4[3] = (bf16)v.w;
    xb[oidx] = bv4;
    s.x += v.x; s.y += v.y; s.z += v.z; s.w += v.w;
  }
  partial0[((size_t)c * 16 + b) * 128 + dq] = s;
}

// ---------------- plain bf16 MFMA GEMM: out(Mx512) = A @ Bt^T, ld 512 --------
__global__ __launch_bounds__(256)
void gemm_plain(const bf16* __restrict__ A, const bf16* __restrict__ Bt,
                bf16* __restrict__ out) {
  constexpr int BK = 32;
  __shared__ __align__(16) bf16 As[128 * BK];
  __shared__ __align__(16) bf16 Bs[128 * BK];
  const int tid = threadIdx.x;
  const int wave = tid >> 6, lane = tid & 63;
  const int wr = wave >> 1, wc = wave & 1;
  const int m0 = blockIdx.x * 128;
  const int n0 = blockIdx.y * 128;
  const int srow = lane >> 2;
  const int skg = ((lane & 3) ^ ((lane >> 3) & 3)) * 8;
  const int fr = lane & 15;
  const int kq = (((lane >> 4) ^ ((lane >> 1) & 3)) & 3) * 8;

  f32x4 acc[4][4];
#pragma unroll
  for (int i = 0; i < 4; ++i)
#pragma unroll
    for (int j = 0; j < 4; ++j) acc[i][j] = (f32x4){0.f, 0.f, 0.f, 0.f};

  for (int kt = 0; kt < 512; kt += BK) {
    __syncthreads();
#pragma unroll
    for (int i = 0; i < 2; ++i) {
      int ch = wave * 2 + i;
      int row = ch * 16 + srow;
      gload_lds16(A + (size_t)(m0 + row) * 512 + kt + skg, &As[ch * 16 * BK]);
      gload_lds16(Bt + (size_t)(n0 + row) * 512 + kt + skg, &Bs[ch * 16 * BK]);
    }
    __syncthreads();

    bf16x8 af[4], bg[4];
#pragma unroll
    for (int i = 0; i < 4; ++i)
      af[i] = *(const bf16x8*)&As[(wr * 64 + i * 16 + fr) * BK + kq];
#pragma unroll
    for (int j = 0; j < 4; ++j)
      bg[j] = *(const bf16x8*)&Bs[(wc * 64 + j * 16 + fr) * BK + kq];
#pragma unroll
    for (int i = 0; i < 4; ++i)
#pragma unroll
      for (int j = 0; j < 4; ++j)
        acc[i][j] = __builtin_amdgcn_mfma_f32_16x16x32_bf16(af[i], bg[j], acc[i][j], 0, 0, 0);
  }

#pragma unroll
  for (int i = 0; i < 4; ++i) {
    int grow0 = m0 + wr * 64 + i * 16 + (lane >> 4) * 4;
#pragma unroll
    for (int j = 0; j < 4; ++j) {
      int gcol = n0 + wc * 64 + j * 16 + fr;
#pragma unroll
      for (int q = 0; q < 4; ++q)
        out[(size_t)(grow0 + q) * 512 + gcol] = (bf16)acc[i][j][q];
    }
  }
}

// ---------------- bf16 MFMA GEMM: YW = A(16384x512) @ [BtY|WvwT_h]^T + bias --
__global__ __launch_bounds__(256)
void gemm_qkw(const bf16* __restrict__ A, const bf16* __restrict__ BtY,
              const bf16* __restrict__ BtVW, const float* __restrict__ biasY,
              const float* __restrict__ biasVW, bf16* __restrict__ out) {
  constexpr int BK = 32;
  __shared__ __align__(16) bf16 As[128 * BK];
  __shared__ __align__(16) bf16 Bs[128 * BK];
  const int tid = threadIdx.x;
  const int wave = tid >> 6, lane = tid & 63;
  const int wr = wave >> 1, wc = wave & 1;
  const int bid = blockIdx.x;                     // 0..1023
  const int swz = (bid & 7) * 128 + (bid >> 3);   // XCD-chunked
  const int m0 = (swz >> 3) * 128;
  const int n0 = (swz & 7) * 128;
  const bf16* Bt = (n0 < 512) ? BtY : (BtVW - (size_t)512 * 512);
  const float* bias = (n0 < 512) ? biasY : (biasVW - 512);

  const int srow = lane >> 2;
  const int skg = ((lane & 3) ^ ((lane >> 3) & 3)) * 8;
  const int fr = lane & 15;
  const int kq = (((lane >> 4) ^ ((lane >> 1) & 3)) & 3) * 8;

  f32x4 acc[4][4];
#pragma unroll
  for (int i = 0; i < 4; ++i)
#pragma unroll
    for (int j = 0; j < 4; ++j) acc[i][j] = (f32x4){0.f, 0.f, 0.f, 0.f};

  for (int kt = 0; kt < 512; kt += BK) {
    __syncthreads();
#pragma unroll
    for (int i = 0; i < 2; ++i) {
      int ch = wave * 2 + i;
      int row = ch * 16 + srow;
      gload_lds16(A + (size_t)(m0 + row) * 512 + kt + skg, &As[ch * 16 * BK]);
      gload_lds16(Bt + (size_t)(n0 + row) * 512 + kt + skg, &Bs[ch * 16 * BK]);
    }
    __syncthreads();

    bf16x8 af[4], bg[4];
#pragma unroll
    for (int i = 0; i < 4; ++i)
      af[i] = *(const bf16x8*)&As[(wr * 64 + i * 16 + fr) * BK + kq];
#pragma unroll
    for (int j = 0; j < 4; ++j)
      bg[j] = *(const bf16x8*)&Bs[(wc * 64 + j * 16 + fr) * BK + kq];
#pragma unroll
    for (int i = 0; i < 4; ++i)
#pragma unroll
      for (int j = 0; j < 4; ++j)
        acc[i][j] = __builtin_amdgcn_mfma_f32_16x16x32_bf16(af[i], bg[j], acc[i][j], 0, 0, 0);
  }

#pragma unroll
  for (int i = 0; i < 4; ++i) {
    int grow0 = m0 + wr * 64 + i * 16 + (lane >> 4) * 4;
#pragma unroll
    for (int j = 0; j < 4; ++j) {
      int gcol = n0 + wc * 64 + j * 16 + fr;
      float bvv = bias[gcol];
#pragma unroll
      for (int q = 0; q < 4; ++q)
        out[(size_t)(grow0 + q) * 1024 + gcol] = (bf16)(acc[i][j][q] + bvv);
    }
  }
}

// ---------------- sparse masked attention + hop epilogue + t-mean partials ---
// Block = 512 threads = 8 waves = one (l,b) pair (16 contiguous rows).
// Stage VW tile (16 rows x 512 cols) -> LDS via global_load_lds (2 rows/wave).
// Wave 0: MFMA scores from dense global rows (Y tile x key tile, + temporal
// tile at +256 rows); softmax in D-layout -> P_lds[16][17].
// All waves: PV 2 queries each from LDS; temporal VW row from global.
__global__ __launch_bounds__(512)
void attn_mix(const bf16* __restrict__ YW, const bf16* __restrict__ xin,
              bf16* __restrict__ xout, const float* __restrict__ bhop,
              float* __restrict__ tpart, int first) {
  __shared__ __align__(16) bf16 VW_lds[16 * 512];   // 16 KB
  __shared__ float P_lds[16 * 17];
  __shared__ float slice[8 * 512];                  // 16 KB
  const int tid = threadIdx.x;
  const int wv = tid >> 6;
  const int lane = tid & 63;
  const int bid = blockIdx.x;
  const int pair = ((bid & 7) << 7) | (bid >> 3);   // 128 pairs per XCD chunk
  const int l = pair >> 4;
  const int tile0 = pair << 4;                      // first row of the group

  // ---- stage VW tile: wave wv stages rows 2wv, 2wv+1 (1 KB each) ----
#pragma unroll
  for (int i2 = 0; i2 < 2; ++i2) {
    int j = wv * 2 + i2;
    gload_lds16(YW + (size_t)(tile0 + j) * 1024 + 512 + lane * 8, &VW_lds[j * 512]);
  }

  if (wv == 0) {
    // ---- scores via MFMA from dense global rows ----
    const int fr = lane & 15;
    const int kg = (lane >> 4) * 8;
    const int tro = (l < 63) ? 256 : 0;   // temporal tile offset (rows)
    f32x4 Sc = (f32x4){0.f, 0.f, 0.f, 0.f};
    f32x4 Tc = (f32x4){0.f, 0.f, 0.f, 0.f};
#pragma unroll
    for (int s = 0; s < 16; ++s) {
      bf16x8 af = *(const bf16x8*)(YW + (size_t)(tile0 + fr) * 1024 + s * 32 + kg);
      bf16x8 bk = *(const bf16x8*)(xin + (size_t)(tile0 + fr) * 512 + s * 32 + kg);
      bf16x8 bt = *(const bf16x8*)(xin + (size_t)(tile0 + fr + tro) * 512 + s * 32 + kg);
      Sc = __builtin_amdgcn_mfma_f32_16x16x32_bf16(af, bk, Sc, 0, 0, 0);
      Tc = __builtin_amdgcn_mfma_f32_16x16x32_bf16(af, bt, Tc, 0, 0, 0);
    }
    // ---- softmax in D-layout: lane holds rows 4h+q of column c ----
    const int h = lane >> 4, c = lane & 15;
    const float scale = 0.044194173824159216f;   // 1/sqrt(512)
#pragma unroll
    for (int q = 0; q < 4; ++q) {
      int row = 4 * h + q;
      float sv = (c == row) ? -1e30f : Sc[q] * scale;             // self mask
      float ev = (c == row && l < 63) ? Tc[q] * scale : -1e30f;   // temporal diag
      float mx = fmaxf(sv, ev);
      mx = fmaxf(mx, __shfl_xor(mx, 1));
      mx = fmaxf(mx, __shfl_xor(mx, 2));
      mx = fmaxf(mx, __shfl_xor(mx, 4));
      mx = fmaxf(mx, __shfl_xor(mx, 8));
      float pv = __expf(sv - mx);
      float pe = __expf(ev - mx);
      float dn = pv + pe;
      dn += __shfl_xor(dn, 1);
      dn += __shfl_xor(dn, 2);
      dn += __shfl_xor(dn, 4);
      dn += __shfl_xor(dn, 8);
      float invd = 1.f / dn;
      P_lds[row * 17 + c] = pv * invd;
      if (c == row) P_lds[row * 17 + 16] = pe * invd;
    }
  }
  __syncthreads();   // VW staged + P ready

  // ---- PV: wave handles queries 2wv, 2wv+1; lane owns d = lane*8..+7 ----
  const int d0 = lane * 8;
  float tsum[8] = {0.f, 0.f, 0.f, 0.f, 0.f, 0.f, 0.f, 0.f};
#pragma unroll
  for (int qq = 0; qq < 2; ++qq) {
    const int g = wv * 2 + qq;
    const int r = tile0 + g;
    float acc[8] = {0.f, 0.f, 0.f, 0.f, 0.f, 0.f, 0.f, 0.f};
#pragma unroll
    for (int j = 0; j < 16; ++j) {
      float w = P_lds[g * 17 + j];      // wave-uniform broadcast
      if (w > 0.f) {                    // skips j==g exactly
        bf16x8 vvv = *(const bf16x8*)&VW_lds[j * 512 + d0];
#pragma unroll
        for (int i = 0; i < 8; ++i) acc[i] += w * (float)vvv[i];
      }
    }
    {
      float w = P_lds[g * 17 + 16];
      if (w > 0.f) {                    // zero at l==63
        const bf16* Vrow = YW + (size_t)(r + 256) * 1024 + 512;
        bf16x8 vvv = *(const bf16x8*)(Vrow + d0);
#pragma unroll
        for (int i = 0; i < 8; ++i) acc[i] += w * (float)vvv[i];
      }
    }
    // epilogue: t = relu(mix+bh); xout = xin + t
    size_t idx = (size_t)r * 512 + d0;
    bf16x8 xo = *(const bf16x8*)(xin + idx);
    float4 bh0 = *(const float4*)(bhop + d0);
    float4 bh1 = *(const float4*)(bhop + d0 + 4);
    float bh[8] = {bh0.x, bh0.y, bh0.z, bh0.w, bh1.x, bh1.y, bh1.z, bh1.w};
    bf16x8 ov;
#pragma unroll
    for (int i = 0; i < 8; ++i) {
      float tv = fmaxf(acc[i] + bh[i], 0.f);
      tsum[i] += tv;
      ov[i] = (bf16)((float)xo[i] + tv);
    }
    *(bf16x8*)(xout + idx) = ov;
  }

  // ---- t-mean partials: permuted per-wave slice (R6 layout), 1 barrier ----
  *(float4*)&slice[wv * 512 + lane * 4]       = (float4){tsum[0], tsum[1], tsum[2], tsum[3]};
  *(float4*)&slice[wv * 512 + 256 + lane * 4] = (float4){tsum[4], tsum[5], tsum[6], tsum[7]};
  __syncthreads();
  const int ll = tid >> 3, ii = tid & 7;
  const int p = (ii < 4) ? (ll * 4 + ii) : (256 + ll * 4 + (ii - 4));
  float s2 = 0.f;
#pragma unroll
  for (int w2 = 0; w2 < 8; ++w2) s2 += slice[w2 * 512 + p];
  float* tp = tpart + (size_t)pair * 512 + tid;
  if (first) *tp = s2;
  else       *tp += s2;
}

// ---------------- agg[b][d] = (sum partial0 + sum tpart)/1024 ----------------
__global__ __launch_bounds__(128)
void agg_final(const float* __restrict__ partial0, const float* __restrict__ tpart,
               float* __restrict__ agg) {
  const int b = blockIdx.x, dc = blockIdx.y;
  const int d = dc * 128 + threadIdx.x;
  float s = 0.f;
  for (int c = 0; c < 128; ++c) s += partial0[((size_t)c * 16 + b) * 512 + d];
  for (int l = 0; l < 64; ++l)          // pair = l*16 + b
    s += tpart[(size_t)(l * 16 + b) * 512 + d];
  agg[b * 512 + d] = s * (1.0f / 1024.0f);
}

// ---------------- final MLP ---------------------------------------------------
__global__ __launch_bounds__(256)
void mlp1(const float* __restrict__ agg, const float* __restrict__ W1t,
          const float* __restrict__ b1, float* __restrict__ hdn) {
  const int lane = threadIdx.x & 63;
  const int o = blockIdx.x * 4 + (threadIdx.x >> 6);
  const int b = lane & 15, q = lane >> 4;
  const float4* wp = (const float4*)(W1t + (size_t)o * 512 + q * 128);
  const float4* ap = (const float4*)(agg + b * 512 + q * 128);
  float acc = 0.f;
#pragma unroll
  for (int i = 0; i < 32; ++i) {
    float4 w = wp[i], a = ap[i];
    acc += w.x * a.x + w.y * a.y + w.z * a.z + w.w * a.w;
  }
  acc += __shfl_xor(acc, 16);
  acc += __shfl_xor(acc, 32);
  if (lane < 16) hdn[b * 1024 + o] = fmaxf(acc + b1[o], 0.f);
}

__global__ __launch_bounds__(256)
void mlp2(const float* __restrict__ hdn, const float* __restrict__ W2t,
          const float* __restrict__ b2, float* __restrict__ out) {
  const int lane = threadIdx.x & 63;
  const int o = blockIdx.x * 4 + (threadIdx.x >> 6);
  const int b = lane & 15, q = lane >> 4;
  const float4* wp = (const float4*)(W2t + (size_t)o * 1024 + q * 256);
  const float4* hp = (const float4*)(hdn + b * 1024 + q * 256);
  float acc = 0.f;
#pragma unroll
  for (int i = 0; i < 64; ++i) {
    float4 w = wp[i], h = hp[i];
    acc += w.x * h.x + w.y * h.y + w.z * h.z + w.w * h.w;
  }
  acc += __shfl_xor(acc, 16);
  acc += __shfl_xor(acc, 32);
  if (lane < 16) out[b * 512 + o] = acc + b2[o];
}

// ---------------- launch -----------------------------------------------------
extern "C" void kernel_launch(void* const* d_in, const int* in_sizes, int n_in,
                              void* d_out, int out_size, void* d_ws, size_t ws_size,
                              hipStream_t stream) {
  const float* what   = (const float*)d_in[0];
  const float* action = (const float*)d_in[1];
  const float* result = (const float*)d_in[2];
  const float* Wq = (const float*)d_in[3];
  const float* bq = (const float*)d_in[4];   (void)bq;  // zeros; cancels in softmax
  const float* Wk = (const float*)d_in[5];
  const float* bk = (const float*)d_in[6];   (void)bk;  // zeros; row-const in softmax
  const float* Wv = (const float*)d_in[7];
  const float* bv = (const float*)d_in[8];
  const float* Whop = (const float*)d_in[9];
  const float* bhop = (const float*)d_in[10];
  const float* W1 = (const float*)d_in[11];
  const float* b1 = (const float*)d_in[12];
  const float* W2 = (const float*)d_in[13];
  const float* b2 = (const float*)d_in[14];
  float* out = (float*)d_out;

  char* ws = (char*)d_ws;
  bf16*  xb0    = (bf16*)(ws + 0);               // 16,777,216 B
  bf16*  xb1    = (bf16*)(ws + 16777216);        // 16,777,216 B
  bf16*  QKW    = (bf16*)(ws + 33554432);        // 33,554,432 B (16384x1024)
  // aliases in QKW region: consumed by gemm_plain before hop 0 writes QKW
  bf16*  WhopTb = (bf16*)(ws + 33554432);        //  1,572,864 B (alias)
  bf16*  Wvb    = (bf16*)(ws + 35127296);        //    524,288 B (alias)
  bf16*  Wqb    = (bf16*)(ws + 35651584);        //    524,288 B (alias)
  bf16*  Wkb    = (bf16*)(ws + 36175872);        //    524,288 B (alias)
  bf16*  BtY    = (bf16*)(ws + 67108864);        //    524,288 B (M^T, persistent)
  bf16*  WvwT   = (bf16*)(ws + 67633152);        //  1,572,864 B (3 hops)
  float* zbias  = (float*)(ws + 69206016);       //      2,048 B
  float* bvw    = (float*)(ws + 69208064);       //      6,144 B
  float* W1t    = (float*)(ws + 69214208);       //  2,097,152 B
  float* W2t    = (float*)(ws + 71311360);       //  2,097,152 B
  float* part0  = (float*)(ws + 73408512);       //  4,194,304 B
  float* tpart  = (float*)(ws + 77602816);       //  2,097,152 B (1024*512 f32)
  float* agg    = (float*)(ws + 81797120);       //     32,768 B
  float* hdn    = (float*)(ws + 81829888);       //     65,536 B

  prep_weights<<<10242, 256, 0, stream>>>(Wq, Wk, Wv, Whop, W1, W2,
                                          Wqb, Wkb, Wvb, WhopTb, W1t, W2t, zbias);
  bvw_kernel<<<384, 256, 0, stream>>>(bv, Whop, bvw);
  gemm_plain<<<dim3(12, 4), 256, 0, stream>>>(WhopTb, Wvb, WvwT);    // Wvw per hop
  gemm_plain<<<dim3(4, 4), 256, 0, stream>>>(Wkb, Wqb, BtY);         // M^T = Wk Wq^T
  nodes_kernel<<<dim3(128, 16), 128, 0, stream>>>((const float4*)what, (const float4*)action,
                                                  (const float4*)result, (bf16x4*)xb0,
                                                  (float4*)part0);
  bf16* xcur = xb0;
  bf16* xnxt = xb1;
  for (int h = 0; h < 3; ++h) {
    gemm_qkw<<<1024, 256, 0, stream>>>(xcur, BtY, WvwT + h * 262144,
                                       zbias, bvw + h * 512, QKW);
    attn_mix<<<1024, 512, 0, stream>>>(QKW, xcur, xnxt, bhop + h * 512, tpart,
                                       h == 0 ? 1 : 0);
    bf16* tmp = xcur; xcur = xnxt; xnxt = tmp;
  }
  agg_final<<<dim3(16, 4), 128, 0, stream>>>(part0, tpart, agg);
  mlp1<<<256, 256, 0, stream>>>(agg, W1t, b1, hdn);
  mlp2<<<128, 256, 0, stream>>>(hdn, W2t, b2, out);
}